// Round 2
// baseline (2263.564 us; speedup 1.0000x reference)
//
#include <hip/hip_runtime.h>
#include <hip/hip_bf16.h>
#include <cstdint>
#include <cstddef>

// GraphAttentionLayer: N=30000, E=480000, C=128, H=8, DH=16, NB=32, NA=16, FC=64.
//
// Workspace budget (~156 MB; round-1 crash suspected ws overflow at 543 MB):
//   MSG bf16 [E,128] 122.9MB  (V bf16 aliases it: per-block read-then-write, same rows)
//   Psrc f32 [N,128] 15.4MB   (ACC aliases it after radial_msg_k)
//   Pdst f32 [N,128] 15.4MB   (LG [E,8] f32 aliases it after radial_msg_k; same size)
//   CSR: deg/rowptr/cursor/eids ~2.3MB
//
// Exact segment-softmax: logits stored, max-subtraction done per-node in aggregate_k.

typedef unsigned short u16;
typedef unsigned int u32;
union fu_ { float f; u32 u; };
static __device__ __forceinline__ float lo2f(u32 v) { fu_ x; x.u = v << 16; return x.f; }
static __device__ __forceinline__ float hi2f(u32 v) { fu_ x; x.u = v & 0xFFFF0000u; return x.f; }
static __device__ __forceinline__ u16 f2bf(float f) {
    fu_ x; x.f = f;
    u32 r = (x.u + 0x7FFFu + ((x.u >> 16) & 1u)) >> 16;
    return (u16)r;
}
static __device__ __forceinline__ u32 pack2(float a, float b) {
    return (u32)f2bf(a) | ((u32)f2bf(b) << 16);
}
static __device__ __forceinline__ float sigmoidf_(float x) { return 1.0f / (1.0f + __expf(-x)); }
static __device__ __forceinline__ float siluf_(float x)    { return x * sigmoidf_(x); }
static __device__ __forceinline__ float slreluf_(float x)  { return x * (0.2f + 0.8f * sigmoidf_(x)); }

// ---------------- CSR build ----------------
__global__ void hist_k(const int* __restrict__ dst, int* __restrict__ deg, int E) {
    int i = blockIdx.x * blockDim.x + threadIdx.x;
    if (i < E) atomicAdd(&deg[dst[i]], 1);
}

__global__ void scan_k(const int* __restrict__ deg, int* __restrict__ rowptr,
                       int* __restrict__ cursor, int n) {
    __shared__ int part[1024];
    const int t = threadIdx.x;
    const int C = (n + 1023) / 1024;
    const int lo = t * C;
    const int hi = (lo + C < n) ? (lo + C) : n;
    int s = 0;
    for (int i = lo; i < hi; ++i) s += deg[i];
    part[t] = s;
    __syncthreads();
    for (int off = 1; off < 1024; off <<= 1) {
        int v = part[t];
        int u = (t >= off) ? part[t - off] : 0;
        __syncthreads();
        part[t] = v + u;
        __syncthreads();
    }
    int excl = (t == 0) ? 0 : part[t - 1];
    for (int i = lo; i < hi; ++i) {
        rowptr[i] = excl;
        cursor[i] = excl;
        excl += deg[i];
    }
    if (t == 1023) rowptr[n] = part[1023];
}

__global__ void fill_k(const int* __restrict__ dst, int* __restrict__ cursor,
                       int* __restrict__ eids, int E) {
    int i = blockIdx.x * blockDim.x + threadIdx.x;
    if (i < E) {
        int d = dst[i];
        int p = atomicAdd(&cursor[d], 1);
        eids[p] = i;
    }
}

// ---------------- node-projection / output GEMM (f32, 64-row tile) ----------------
template <int K, int NC>
__global__ __launch_bounds__(256) void gemm_plain_k(const float* __restrict__ A,
                                                    const float* __restrict__ Bw,
                                                    const float* __restrict__ bias,
                                                    float* __restrict__ Out, int M) {
    constexpr int CT = NC / 16;
    __shared__ __align__(16) float As[K * 68];
    __shared__ __align__(16) float Bs[K * NC];
    const int tid = threadIdx.x;
    const int e0 = blockIdx.x * 64;
    for (int i = tid; i < 64 * K; i += 256) {
        int r = i / K, k = i - r * K;
        int row = e0 + r;
        As[k * 68 + r] = (row < M) ? A[(size_t)row * K + k] : 0.0f;
    }
    for (int i = tid; i < K * NC; i += 256) Bs[i] = Bw[i];
    __syncthreads();

    const int eb = (tid >> 4) * 4;
    const int c0 = (tid & 15) * CT;
    float acc[4][CT];
#pragma unroll
    for (int i = 0; i < 4; ++i)
#pragma unroll
        for (int j = 0; j < CT; ++j) acc[i][j] = 0.0f;

#pragma unroll 4
    for (int k = 0; k < K; ++k) {
        const float4 av = *reinterpret_cast<const float4*>(&As[k * 68 + eb]);
        const float a[4] = {av.x, av.y, av.z, av.w};
#pragma unroll
        for (int jj = 0; jj < CT; jj += 4) {
            const float4 bv = *reinterpret_cast<const float4*>(&Bs[k * NC + c0 + jj]);
            const float b[4] = {bv.x, bv.y, bv.z, bv.w};
#pragma unroll
            for (int j = 0; j < 4; ++j)
#pragma unroll
                for (int i = 0; i < 4; ++i) acc[i][jj + j] += a[i] * b[j];
        }
    }

    float bv[CT];
#pragma unroll
    for (int j = 0; j < CT; ++j) bv[j] = bias ? bias[c0 + j] : 0.0f;
    for (int i = 0; i < 4; ++i) {
        int row = e0 + eb + i;
        if (row >= M) break;
        float o[CT];
#pragma unroll
        for (int j = 0; j < CT; ++j) o[j] = acc[i][j] + bv[j];
        float4* dst4 = reinterpret_cast<float4*>(&Out[(size_t)row * NC + c0]);
        dst4[0] = make_float4(o[0], o[1], o[2], o[3]);
        if (CT == 8) dst4[1] = make_float4(o[4], o[5], o[6], o[7]);
    }
}

// ---------------- fused radial MLP + message (LDS ~99 KB) ----------------
__global__ __launch_bounds__(256) void radial_msg_k(
    const float* __restrict__ eemb, const float* __restrict__ nattr,
    const float* __restrict__ ea,
    const int* __restrict__ src, const int* __restrict__ dst,
    const float* __restrict__ W1, const float* __restrict__ b1,
    const float* __restrict__ W2, const float* __restrict__ b2,
    const float* __restrict__ W3,
    const float* __restrict__ Ps, const float* __restrict__ Pd,
    u16* __restrict__ MSG, int E) {
    __shared__ __align__(16) float WFs[64 * 68];   // transposed [k][r]
    __shared__ __align__(16) float Hs[64 * 68];    // transposed
    __shared__ __align__(16) float W1s[64 * 64];
    __shared__ __align__(16) float W2s[64 * 64];
    __shared__ __align__(16) float W3s[64 * 128];
    __shared__ float b1s[64], b2s[64], ea_l[64];
    __shared__ int src_l[64], dst_l[64];

    const int tid = threadIdx.x;
    const int e0 = blockIdx.x * 64;

    if (tid < 64) {
        int row = e0 + tid;
        bool v = row < E;
        ea_l[tid]  = v ? ea[row] : 0.0f;
        src_l[tid] = v ? src[row] : 0;
        dst_l[tid] = v ? dst[row] : 0;
        b1s[tid] = b1[tid];
        b2s[tid] = b2[tid];
    }
    for (int i = tid; i < 4096; i += 256) { W1s[i] = W1[i]; W2s[i] = W2[i]; }
    for (int i = tid; i < 8192; i += 256) W3s[i] = W3[i];
    __syncthreads();

    // gather WF = [eemb | na[src] | na[dst]] transposed into WFs
    for (int i = tid; i < 4096; i += 256) {
        int r = i >> 6, k = i & 63;
        int row = e0 + r;
        float v = 0.0f;
        if (row < E) {
            if (k < 32)      v = eemb[(size_t)row * 32 + k];
            else if (k < 48) v = nattr[(size_t)src_l[r] * 16 + (k - 32)];
            else             v = nattr[(size_t)dst_l[r] * 16 + (k - 48)];
        }
        WFs[k * 68 + r] = v;
    }
    __syncthreads();

    const int eb = (tid >> 4) * 4;
    const int c4 = (tid & 15) * 4;
    const int c8 = (tid & 15) * 8;
    float acc[4][4];

    // fc1: H = silu(WF@W1 + b1)
#pragma unroll
    for (int i = 0; i < 4; ++i)
#pragma unroll
        for (int j = 0; j < 4; ++j) acc[i][j] = 0.0f;
#pragma unroll 4
    for (int k = 0; k < 64; ++k) {
        const float4 av = *reinterpret_cast<const float4*>(&WFs[k * 68 + eb]);
        const float4 bv = *reinterpret_cast<const float4*>(&W1s[k * 64 + c4]);
        const float a[4] = {av.x, av.y, av.z, av.w};
        const float b[4] = {bv.x, bv.y, bv.z, bv.w};
#pragma unroll
        for (int j = 0; j < 4; ++j)
#pragma unroll
            for (int i = 0; i < 4; ++i) acc[i][j] += a[i] * b[j];
    }
#pragma unroll
    for (int j = 0; j < 4; ++j)
#pragma unroll
        for (int i = 0; i < 4; ++i) Hs[(c4 + j) * 68 + eb + i] = siluf_(acc[i][j] + b1s[c4 + j]);
    __syncthreads();

    // fc2: WFs = silu(H@W2 + b2)   (WFs reusable: all fc1 reads done before sync)
#pragma unroll
    for (int i = 0; i < 4; ++i)
#pragma unroll
        for (int j = 0; j < 4; ++j) acc[i][j] = 0.0f;
#pragma unroll 4
    for (int k = 0; k < 64; ++k) {
        const float4 av = *reinterpret_cast<const float4*>(&Hs[k * 68 + eb]);
        const float4 bv = *reinterpret_cast<const float4*>(&W2s[k * 64 + c4]);
        const float a[4] = {av.x, av.y, av.z, av.w};
        const float b[4] = {bv.x, bv.y, bv.z, bv.w};
#pragma unroll
        for (int j = 0; j < 4; ++j)
#pragma unroll
            for (int i = 0; i < 4; ++i) acc[i][j] += a[i] * b[j];
    }
    __syncthreads();  // ensure fc2 reads of Hs done everywhere before anyone proceeds; also WFs reads done
#pragma unroll
    for (int j = 0; j < 4; ++j)
#pragma unroll
        for (int i = 0; i < 4; ++i) WFs[(c4 + j) * 68 + eb + i] = siluf_(acc[i][j] + b2s[c4 + j]);
    __syncthreads();

    // fc3 + message: MSG = (Ps[src]+Pd[dst]) * ea * (H2@W3)
    float acc8[4][8];
#pragma unroll
    for (int i = 0; i < 4; ++i)
#pragma unroll
        for (int j = 0; j < 8; ++j) acc8[i][j] = 0.0f;
#pragma unroll 4
    for (int k = 0; k < 64; ++k) {
        const float4 av = *reinterpret_cast<const float4*>(&WFs[k * 68 + eb]);
        const float4 b0 = *reinterpret_cast<const float4*>(&W3s[k * 128 + c8]);
        const float4 b1v = *reinterpret_cast<const float4*>(&W3s[k * 128 + c8 + 4]);
        const float a[4] = {av.x, av.y, av.z, av.w};
        const float b[8] = {b0.x, b0.y, b0.z, b0.w, b1v.x, b1v.y, b1v.z, b1v.w};
#pragma unroll
        for (int j = 0; j < 8; ++j)
#pragma unroll
            for (int i = 0; i < 4; ++i) acc8[i][j] += a[i] * b[j];
    }
    for (int i = 0; i < 4; ++i) {
        const int el = eb + i;
        const int row = e0 + el;
        if (row >= E) break;
        const float eav = ea_l[el];
        const int s = src_l[el], d = dst_l[el];
        const float4 ps0 = *reinterpret_cast<const float4*>(&Ps[(size_t)s * 128 + c8]);
        const float4 ps1 = *reinterpret_cast<const float4*>(&Ps[(size_t)s * 128 + c8 + 4]);
        const float4 pd0 = *reinterpret_cast<const float4*>(&Pd[(size_t)d * 128 + c8]);
        const float4 pd1 = *reinterpret_cast<const float4*>(&Pd[(size_t)d * 128 + c8 + 4]);
        float m[8];
        m[0] = (ps0.x + pd0.x) * eav * acc8[i][0];
        m[1] = (ps0.y + pd0.y) * eav * acc8[i][1];
        m[2] = (ps0.z + pd0.z) * eav * acc8[i][2];
        m[3] = (ps0.w + pd0.w) * eav * acc8[i][3];
        m[4] = (ps1.x + pd1.x) * eav * acc8[i][4];
        m[5] = (ps1.y + pd1.y) * eav * acc8[i][5];
        m[6] = (ps1.z + pd1.z) * eav * acc8[i][6];
        m[7] = (ps1.w + pd1.w) * eav * acc8[i][7];
        u32 p0 = pack2(m[0], m[1]), p1 = pack2(m[2], m[3]);
        u32 p2 = pack2(m[4], m[5]), p3 = pack2(m[6], m[7]);
        uint4* o = reinterpret_cast<uint4*>(&MSG[(size_t)row * 128 + c8]);
        *o = make_uint4(p0, p1, p2, p3);
    }
}

// ---------------- fused attention logits + value path (LDS ~148 KB) ----------------
__global__ __launch_bounds__(256) void attn_val_k(
    const u16* __restrict__ MSG,
    const float* __restrict__ Wa, const float* __restrict__ Wl,
    const float* __restrict__ Wv,
    const float* __restrict__ att_dot, const float* __restrict__ w_int,
    const float* __restrict__ ea,
    float* __restrict__ LG, u16* __restrict__ V, int E) {
    __shared__ __align__(16) float As[128 * 68];   // MSG tile transposed, f32
    __shared__ __align__(16) u16 Wcs[128 * 256];   // [Wa | Wl] bf16
    __shared__ __align__(16) u16 Wvs[128 * 128];   // Wv bf16
    __shared__ __align__(16) u16 V1s[128 * 68];    // V1 transposed bf16
    __shared__ float adl[128], wil[128], ea_l[64];

    const int tid = threadIdx.x;
    const int e0 = blockIdx.x * 64;

    if (tid < 64) {
        int row = e0 + tid;
        ea_l[tid] = (row < E) ? ea[row] : 0.0f;
    }
    if (tid < 128) {
        adl[tid] = att_dot[tid];
        wil[tid] = w_int[tid];
    }
    // stage [Wa|Wl] as bf16
    for (int i = tid; i < 8192; i += 256) {
        int k = i >> 6, c4 = (i & 63) * 4;
        float4 wv = (c4 < 128)
                        ? *reinterpret_cast<const float4*>(&Wa[(size_t)k * 128 + c4])
                        : *reinterpret_cast<const float4*>(&Wl[(size_t)k * 128 + (c4 - 128)]);
        u32 p0 = pack2(wv.x, wv.y), p1 = pack2(wv.z, wv.w);
        *reinterpret_cast<uint2*>(&Wcs[k * 256 + c4]) = make_uint2(p0, p1);
    }
    for (int i = tid; i < 4096; i += 256) {
        int k = i >> 5, c4 = (i & 31) * 4;
        float4 wv = *reinterpret_cast<const float4*>(&Wv[(size_t)k * 128 + c4]);
        u32 p0 = pack2(wv.x, wv.y), p1 = pack2(wv.z, wv.w);
        *reinterpret_cast<uint2*>(&Wvs[k * 128 + c4]) = make_uint2(p0, p1);
    }
    // stage MSG tile transposed (bf16 -> f32)
    for (int i = tid; i < 2048; i += 256) {
        int r = i >> 5, k4 = (i & 31) * 4;
        int row = e0 + r;
        uint2 d = make_uint2(0u, 0u);
        if (row < E) d = *reinterpret_cast<const uint2*>(&MSG[(size_t)row * 128 + k4]);
        As[(k4 + 0) * 68 + r] = lo2f(d.x);
        As[(k4 + 1) * 68 + r] = hi2f(d.x);
        As[(k4 + 2) * 68 + r] = lo2f(d.y);
        As[(k4 + 3) * 68 + r] = hi2f(d.y);
    }
    __syncthreads();

    const int eb = (tid >> 4) * 4;
    const int c0 = (tid & 15) * 16;  // col in [0,256): <128 attn scores, >=128 value-lin

    float acc[4][16];
#pragma unroll
    for (int i = 0; i < 4; ++i)
#pragma unroll
        for (int j = 0; j < 16; ++j) acc[i][j] = 0.0f;

#pragma unroll 2
    for (int k = 0; k < 128; ++k) {
        const float4 av = *reinterpret_cast<const float4*>(&As[k * 68 + eb]);
        const float a[4] = {av.x, av.y, av.z, av.w};
        const uint2* bp = reinterpret_cast<const uint2*>(&Wcs[k * 256 + c0]);
        const uint2 b0 = bp[0], b1 = bp[1], b2 = bp[2], b3 = bp[3];
        const float b[16] = {lo2f(b0.x), hi2f(b0.x), lo2f(b0.y), hi2f(b0.y),
                             lo2f(b1.x), hi2f(b1.x), lo2f(b1.y), hi2f(b1.y),
                             lo2f(b2.x), hi2f(b2.x), lo2f(b2.y), hi2f(b2.y),
                             lo2f(b3.x), hi2f(b3.x), lo2f(b3.y), hi2f(b3.y)};
#pragma unroll
        for (int j = 0; j < 16; ++j)
#pragma unroll
            for (int i = 0; i < 4; ++i) acc[i][j] += a[i] * b[j];
    }

    if (c0 < 128) {
        // this thread's 16 cols are exactly one head
        const int h = c0 >> 4;
#pragma unroll
        for (int i = 0; i < 4; ++i) {
            int row = e0 + eb + i;
            if (row < E) {
                float p = 0.0f;
#pragma unroll
                for (int j = 0; j < 16; ++j) p += slreluf_(acc[i][j]) * adl[c0 + j];
                LG[(size_t)row * 8 + h] = p;
            }
        }
    } else {
        const int cc = c0 - 128;
#pragma unroll
        for (int i = 0; i < 4; ++i) {
            const int el = eb + i;
#pragma unroll
            for (int j = 0; j < 16; ++j) {
                float v1 = siluf_(acc[i][j]) * ea_l[el] * wil[cc + j];
                V1s[(cc + j) * 68 + el] = f2bf(v1);
            }
        }
    }
    __syncthreads();

    // GEMM2: V = V1 @ Wv
    const int c0b = (tid & 15) * 8;
    float acc2[4][8];
#pragma unroll
    for (int i = 0; i < 4; ++i)
#pragma unroll
        for (int j = 0; j < 8; ++j) acc2[i][j] = 0.0f;

#pragma unroll 4
    for (int k = 0; k < 128; ++k) {
        const uint2 a2 = *reinterpret_cast<const uint2*>(&V1s[k * 68 + eb]);
        const float a[4] = {lo2f(a2.x), hi2f(a2.x), lo2f(a2.y), hi2f(a2.y)};
        const uint4 b4 = *reinterpret_cast<const uint4*>(&Wvs[k * 128 + c0b]);
        const float b[8] = {lo2f(b4.x), hi2f(b4.x), lo2f(b4.y), hi2f(b4.y),
                            lo2f(b4.z), hi2f(b4.z), lo2f(b4.w), hi2f(b4.w)};
#pragma unroll
        for (int j = 0; j < 8; ++j)
#pragma unroll
            for (int i = 0; i < 4; ++i) acc2[i][j] += a[i] * b[j];
    }
    for (int i = 0; i < 4; ++i) {
        int row = e0 + eb + i;
        if (row >= E) break;
        u32 p0 = pack2(acc2[i][0], acc2[i][1]), p1 = pack2(acc2[i][2], acc2[i][3]);
        u32 p2 = pack2(acc2[i][4], acc2[i][5]), p3 = pack2(acc2[i][6], acc2[i][7]);
        uint4* o = reinterpret_cast<uint4*>(&V[(size_t)row * 128 + c0b]);
        *o = make_uint4(p0, p1, p2, p3);  // V aliases MSG: reads finished before 1st sync
    }
}

// ---------------- CSR aggregation with exact per-node max subtraction ----------------
__global__ __launch_bounds__(256) void aggregate_k(const int* __restrict__ rowptr,
                                                   const int* __restrict__ eids,
                                                   const float* __restrict__ LG,
                                                   const u16* __restrict__ V,
                                                   float* __restrict__ ACC, int Nn) {
    const int node = blockIdx.x * 4 + (threadIdx.x >> 6);
    const int lane = threadIdx.x & 63;
    if (node >= Nn) return;
    const int s = rowptr[node], t = rowptr[node + 1];
    const int h = lane >> 3;  // cols (2*lane, 2*lane+1) -> head (2*lane)/16
    float m = -3.4e38f;
    for (int i = s; i < t; ++i) {
        const int e = eids[i];
        m = fmaxf(m, LG[(size_t)e * 8 + h]);
    }
    float a0 = 0.0f, a1 = 0.0f, ds = 0.0f;
    for (int i = s; i < t; ++i) {
        const int e = eids[i];
        const float exv = __expf(LG[(size_t)e * 8 + h] - m);
        const u32 vv = *reinterpret_cast<const u32*>(&V[(size_t)e * 128 + lane * 2]);
        a0 += exv * lo2f(vv);
        a1 += exv * hi2f(vv);
        ds += exv;
    }
    const float inv = 1.0f / (ds + 1e-16f);
    ACC[(size_t)node * 128 + lane * 2]     = a0 * inv;
    ACC[(size_t)node * 128 + lane * 2 + 1] = a1 * inv;
}

// ---------------- launch ----------------
extern "C" void kernel_launch(void* const* d_in, const int* in_sizes, int n_in,
                              void* d_out, int out_size, void* d_ws, size_t ws_size,
                              hipStream_t stream) {
    const float* node_feats = (const float*)d_in[0];
    const float* node_attr  = (const float*)d_in[1];
    const float* edge_attr  = (const float*)d_in[2];
    const float* edge_emb   = (const float*)d_in[3];
    const float* W_src      = (const float*)d_in[4];
    const float* b_src      = (const float*)d_in[5];
    const float* W_dst      = (const float*)d_in[6];
    const float* W_fc1      = (const float*)d_in[7];
    const float* b_fc1      = (const float*)d_in[8];
    const float* W_fc2      = (const float*)d_in[9];
    const float* b_fc2      = (const float*)d_in[10];
    const float* W_fc3      = (const float*)d_in[11];
    const float* W_alpha    = (const float*)d_in[12];
    const float* W_lin      = (const float*)d_in[13];
    const float* w_int      = (const float*)d_in[14];
    const float* W_val      = (const float*)d_in[15];
    const float* att_dot    = (const float*)d_in[16];
    const float* W_out      = (const float*)d_in[17];
    const float* b_out      = (const float*)d_in[18];
    const int* esrc         = (const int*)d_in[19];
    const int* edst         = (const int*)d_in[20];

    const int Nn = in_sizes[0] / 128;  // 30000
    const int E  = in_sizes[19];       // 480000

    char* w = (char*)d_ws;
    auto alloc = [&](size_t bytes) {
        char* p = w;
        w += (bytes + 255) & ~(size_t)255;
        return p;
    };
    // MSG bf16 [E,128]; V aliases it (safe: per-block stage-then-overwrite, same rows)
    u16* MSG = (u16*)alloc((size_t)E * 128 * 2);
    u16* V   = MSG;
    // Psrc; ACC aliases it (Psrc dead after radial_msg_k)
    float* Psrc = (float*)alloc((size_t)Nn * 128 * 4);
    float* ACC  = Psrc;
    // Pdst; LG [E,8] aliases it (same byte size: N*128*4 == E*8*4)
    float* Pdst = (float*)alloc((size_t)Nn * 128 * 4 > (size_t)E * 8 * 4
                                    ? (size_t)Nn * 128 * 4 : (size_t)E * 8 * 4);
    float* LG   = Pdst;
    int* deg    = (int*)alloc((size_t)Nn * 4);
    int* rowptr = (int*)alloc((size_t)(Nn + 1) * 4);
    int* cursor = (int*)alloc((size_t)Nn * 4);
    int* eids   = (int*)alloc((size_t)E * 4);

    // CSR build
    hipMemsetAsync(deg, 0, (size_t)Nn * 4, stream);
    hist_k<<<(E + 255) / 256, 256, 0, stream>>>(edst, deg, E);
    scan_k<<<1, 1024, 0, stream>>>(deg, rowptr, cursor, Nn);
    fill_k<<<(E + 255) / 256, 256, 0, stream>>>(edst, cursor, eids, E);

    const int nb_node = (Nn + 63) / 64;  // 469
    const int nb_e    = (E + 63) / 64;   // 7500

    // node projections
    gemm_plain_k<128, 128><<<nb_node, 256, 0, stream>>>(node_feats, W_src, b_src, Psrc, Nn);
    gemm_plain_k<128, 128><<<nb_node, 256, 0, stream>>>(node_feats, W_dst, nullptr, Pdst, Nn);

    // fused radial MLP + message
    radial_msg_k<<<nb_e, 256, 0, stream>>>(edge_emb, node_attr, edge_attr, esrc, edst,
                                           W_fc1, b_fc1, W_fc2, b_fc2, W_fc3,
                                           Psrc, Pdst, MSG, E);

    // fused attention logits + value path (LG overwrites Pdst region; V overwrites MSG)
    attn_val_k<<<nb_e, 256, 0, stream>>>(MSG, W_alpha, W_lin, W_val,
                                         att_dot, w_int, edge_attr, LG, V, E);

    // segment softmax + weighted aggregation (ACC overwrites Psrc region)
    aggregate_k<<<(Nn + 3) / 4, 256, 0, stream>>>(rowptr, eids, LG, V, ACC, Nn);

    // output projection
    gemm_plain_k<128, 128><<<nb_node, 256, 0, stream>>>(ACC, W_out, b_out, (float*)d_out, Nn);
}

// Round 4
// 1401.167 us; speedup vs baseline: 1.6155x; 1.6155x over previous
//
#include <hip/hip_runtime.h>
#include <hip/hip_bf16.h>
#include <cstdint>
#include <cstddef>

// GraphAttentionLayer: N=30000, E=480000, C=128, H=8, DH=16, NB=32, NA=16, FC=64.
//
// R4 == R3 resubmission (R3 bench died on infra: UnresponsiveContainer; kernel
// never ran). attn_val_k on v_mfma_f32_16x16x32_bf16:
//   - B operands (weights) pre-transposed to bf16 once (prep_w_k), read per-lane
//     from global (L2-resident, ~98 KB) -- no weight LDS.
//   - A operand (MSG bf16) read per-lane from global (tile L1-resident).
//   - Only V1 (GEMM1->GEMM2 intermediate) goes through LDS, XOR-swizzled
//     (byte ^= (row&7)<<4) for conflict-free ds_read_b128.
//   - Logits via 16-lane shfl_xor reduction.
// Exact segment softmax kept: LG stored, max-sub in aggregate_k.

typedef unsigned short u16;
typedef unsigned int u32;
typedef __attribute__((ext_vector_type(8))) short bf16x8;
typedef __attribute__((ext_vector_type(4))) float f32x4;

union fu_ { float f; u32 u; };
static __device__ __forceinline__ float lo2f(u32 v) { fu_ x; x.u = v << 16; return x.f; }
static __device__ __forceinline__ float hi2f(u32 v) { fu_ x; x.u = v & 0xFFFF0000u; return x.f; }
static __device__ __forceinline__ u16 f2bf(float f) {
    fu_ x; x.f = f;
    u32 r = (x.u + 0x7FFFu + ((x.u >> 16) & 1u)) >> 16;
    return (u16)r;
}
static __device__ __forceinline__ u32 pack2(float a, float b) {
    return (u32)f2bf(a) | ((u32)f2bf(b) << 16);
}
static __device__ __forceinline__ float sigmoidf_(float x) { return 1.0f / (1.0f + __expf(-x)); }
static __device__ __forceinline__ float siluf_(float x)    { return x * sigmoidf_(x); }
static __device__ __forceinline__ float slreluf_(float x)  { return x * (0.2f + 0.8f * sigmoidf_(x)); }

#define MFMA16(a, b, c) __builtin_amdgcn_mfma_f32_16x16x32_bf16((a), (b), (c), 0, 0, 0)

// ---------------- CSR build ----------------
__global__ void hist_k(const int* __restrict__ dst, int* __restrict__ deg, int E) {
    int i = blockIdx.x * blockDim.x + threadIdx.x;
    if (i < E) atomicAdd(&deg[dst[i]], 1);
}

__global__ void scan_k(const int* __restrict__ deg, int* __restrict__ rowptr,
                       int* __restrict__ cursor, int n) {
    __shared__ int part[1024];
    const int t = threadIdx.x;
    const int C = (n + 1023) / 1024;
    const int lo = t * C;
    const int hi = (lo + C < n) ? (lo + C) : n;
    int s = 0;
    for (int i = lo; i < hi; ++i) s += deg[i];
    part[t] = s;
    __syncthreads();
    for (int off = 1; off < 1024; off <<= 1) {
        int v = part[t];
        int u = (t >= off) ? part[t - off] : 0;
        __syncthreads();
        part[t] = v + u;
        __syncthreads();
    }
    int excl = (t == 0) ? 0 : part[t - 1];
    for (int i = lo; i < hi; ++i) {
        rowptr[i] = excl;
        cursor[i] = excl;
        excl += deg[i];
    }
    if (t == 1023) rowptr[n] = part[1023];
}

__global__ void fill_k(const int* __restrict__ dst, int* __restrict__ cursor,
                       int* __restrict__ eids, int E) {
    int i = blockIdx.x * blockDim.x + threadIdx.x;
    if (i < E) {
        int d = dst[i];
        int p = atomicAdd(&cursor[d], 1);
        eids[p] = i;
    }
}

// ---------------- weight prep: Wct[c][k] = [Wa|Wl] transposed bf16; Wvt[j][c] = Wv^T bf16 ----
__global__ void prep_w_k(const float* __restrict__ Wa, const float* __restrict__ Wl,
                         const float* __restrict__ Wv,
                         u16* __restrict__ Wct, u16* __restrict__ Wvt) {
    int idx = blockIdx.x * 256 + threadIdx.x;
    if (idx < 32768) {  // Wct: 256 cols x 128 k
        int c = idx >> 7, k = idx & 127;
        float v = (c < 128) ? Wa[(size_t)k * 128 + c] : Wl[(size_t)k * 128 + (c - 128)];
        Wct[idx] = f2bf(v);
    } else if (idx < 49152) {  // Wvt: 128 j x 128 c
        int t = idx - 32768;
        int j = t >> 7, c = t & 127;
        Wvt[t] = f2bf(Wv[(size_t)c * 128 + j]);
    }
}

// ---------------- node-projection / output GEMM (f32, 64-row tile) ----------------
template <int K, int NC>
__global__ __launch_bounds__(256) void gemm_plain_k(const float* __restrict__ A,
                                                    const float* __restrict__ Bw,
                                                    const float* __restrict__ bias,
                                                    float* __restrict__ Out, int M) {
    constexpr int CT = NC / 16;
    __shared__ __align__(16) float As[K * 68];
    __shared__ __align__(16) float Bs[K * NC];
    const int tid = threadIdx.x;
    const int e0 = blockIdx.x * 64;
    for (int i = tid; i < 64 * K; i += 256) {
        int r = i / K, k = i - r * K;
        int row = e0 + r;
        As[k * 68 + r] = (row < M) ? A[(size_t)row * K + k] : 0.0f;
    }
    for (int i = tid; i < K * NC; i += 256) Bs[i] = Bw[i];
    __syncthreads();

    const int eb = (tid >> 4) * 4;
    const int c0 = (tid & 15) * CT;
    float acc[4][CT];
#pragma unroll
    for (int i = 0; i < 4; ++i)
#pragma unroll
        for (int j = 0; j < CT; ++j) acc[i][j] = 0.0f;

#pragma unroll 4
    for (int k = 0; k < K; ++k) {
        const float4 av = *reinterpret_cast<const float4*>(&As[k * 68 + eb]);
        const float a[4] = {av.x, av.y, av.z, av.w};
#pragma unroll
        for (int jj = 0; jj < CT; jj += 4) {
            const float4 bv = *reinterpret_cast<const float4*>(&Bs[k * NC + c0 + jj]);
            const float b[4] = {bv.x, bv.y, bv.z, bv.w};
#pragma unroll
            for (int j = 0; j < 4; ++j)
#pragma unroll
                for (int i = 0; i < 4; ++i) acc[i][jj + j] += a[i] * b[j];
        }
    }

    float bv[CT];
#pragma unroll
    for (int j = 0; j < CT; ++j) bv[j] = bias ? bias[c0 + j] : 0.0f;
    for (int i = 0; i < 4; ++i) {
        int row = e0 + eb + i;
        if (row >= M) break;
        float o[CT];
#pragma unroll
        for (int j = 0; j < CT; ++j) o[j] = acc[i][j] + bv[j];
        float4* dst4 = reinterpret_cast<float4*>(&Out[(size_t)row * NC + c0]);
        dst4[0] = make_float4(o[0], o[1], o[2], o[3]);
        if (CT == 8) dst4[1] = make_float4(o[4], o[5], o[6], o[7]);
    }
}

// ---------------- fused radial MLP + message (f32 VALU) ----------------
__global__ __launch_bounds__(256) void radial_msg_k(
    const float* __restrict__ eemb, const float* __restrict__ nattr,
    const float* __restrict__ ea,
    const int* __restrict__ src, const int* __restrict__ dst,
    const float* __restrict__ W1, const float* __restrict__ b1,
    const float* __restrict__ W2, const float* __restrict__ b2,
    const float* __restrict__ W3,
    const float* __restrict__ Ps, const float* __restrict__ Pd,
    u16* __restrict__ MSG, int E) {
    __shared__ __align__(16) float WFs[64 * 68];
    __shared__ __align__(16) float Hs[64 * 68];
    __shared__ __align__(16) float W1s[64 * 64];
    __shared__ __align__(16) float W2s[64 * 64];
    __shared__ __align__(16) float W3s[64 * 128];
    __shared__ float b1s[64], b2s[64], ea_l[64];
    __shared__ int src_l[64], dst_l[64];

    const int tid = threadIdx.x;
    const int e0 = blockIdx.x * 64;

    if (tid < 64) {
        int row = e0 + tid;
        bool v = row < E;
        ea_l[tid]  = v ? ea[row] : 0.0f;
        src_l[tid] = v ? src[row] : 0;
        dst_l[tid] = v ? dst[row] : 0;
        b1s[tid] = b1[tid];
        b2s[tid] = b2[tid];
    }
    for (int i = tid; i < 4096; i += 256) { W1s[i] = W1[i]; W2s[i] = W2[i]; }
    for (int i = tid; i < 8192; i += 256) W3s[i] = W3[i];
    __syncthreads();

    for (int i = tid; i < 4096; i += 256) {
        int r = i >> 6, k = i & 63;
        int row = e0 + r;
        float v = 0.0f;
        if (row < E) {
            if (k < 32)      v = eemb[(size_t)row * 32 + k];
            else if (k < 48) v = nattr[(size_t)src_l[r] * 16 + (k - 32)];
            else             v = nattr[(size_t)dst_l[r] * 16 + (k - 48)];
        }
        WFs[k * 68 + r] = v;
    }
    __syncthreads();

    const int eb = (tid >> 4) * 4;
    const int c4 = (tid & 15) * 4;
    const int c8 = (tid & 15) * 8;
    float acc[4][4];

#pragma unroll
    for (int i = 0; i < 4; ++i)
#pragma unroll
        for (int j = 0; j < 4; ++j) acc[i][j] = 0.0f;
#pragma unroll 4
    for (int k = 0; k < 64; ++k) {
        const float4 av = *reinterpret_cast<const float4*>(&WFs[k * 68 + eb]);
        const float4 bv = *reinterpret_cast<const float4*>(&W1s[k * 64 + c4]);
        const float a[4] = {av.x, av.y, av.z, av.w};
        const float b[4] = {bv.x, bv.y, bv.z, bv.w};
#pragma unroll
        for (int j = 0; j < 4; ++j)
#pragma unroll
            for (int i = 0; i < 4; ++i) acc[i][j] += a[i] * b[j];
    }
#pragma unroll
    for (int j = 0; j < 4; ++j)
#pragma unroll
        for (int i = 0; i < 4; ++i) Hs[(c4 + j) * 68 + eb + i] = siluf_(acc[i][j] + b1s[c4 + j]);
    __syncthreads();

#pragma unroll
    for (int i = 0; i < 4; ++i)
#pragma unroll
        for (int j = 0; j < 4; ++j) acc[i][j] = 0.0f;
#pragma unroll 4
    for (int k = 0; k < 64; ++k) {
        const float4 av = *reinterpret_cast<const float4*>(&Hs[k * 68 + eb]);
        const float4 bv = *reinterpret_cast<const float4*>(&W2s[k * 64 + c4]);
        const float a[4] = {av.x, av.y, av.z, av.w};
        const float b[4] = {bv.x, bv.y, bv.z, bv.w};
#pragma unroll
        for (int j = 0; j < 4; ++j)
#pragma unroll
            for (int i = 0; i < 4; ++i) acc[i][j] += a[i] * b[j];
    }
    __syncthreads();
#pragma unroll
    for (int j = 0; j < 4; ++j)
#pragma unroll
        for (int i = 0; i < 4; ++i) WFs[(c4 + j) * 68 + eb + i] = siluf_(acc[i][j] + b2s[c4 + j]);
    __syncthreads();

    float acc8[4][8];
#pragma unroll
    for (int i = 0; i < 4; ++i)
#pragma unroll
        for (int j = 0; j < 8; ++j) acc8[i][j] = 0.0f;
#pragma unroll 4
    for (int k = 0; k < 64; ++k) {
        const float4 av = *reinterpret_cast<const float4*>(&WFs[k * 68 + eb]);
        const float4 b0 = *reinterpret_cast<const float4*>(&W3s[k * 128 + c8]);
        const float4 b1v = *reinterpret_cast<const float4*>(&W3s[k * 128 + c8 + 4]);
        const float a[4] = {av.x, av.y, av.z, av.w};
        const float b[8] = {b0.x, b0.y, b0.z, b0.w, b1v.x, b1v.y, b1v.z, b1v.w};
#pragma unroll
        for (int j = 0; j < 8; ++j)
#pragma unroll
            for (int i = 0; i < 4; ++i) acc8[i][j] += a[i] * b[j];
    }
    for (int i = 0; i < 4; ++i) {
        const int el = eb + i;
        const int row = e0 + el;
        if (row >= E) break;
        const float eav = ea_l[el];
        const int s = src_l[el], d = dst_l[el];
        const float4 ps0 = *reinterpret_cast<const float4*>(&Ps[(size_t)s * 128 + c8]);
        const float4 ps1 = *reinterpret_cast<const float4*>(&Ps[(size_t)s * 128 + c8 + 4]);
        const float4 pd0 = *reinterpret_cast<const float4*>(&Pd[(size_t)d * 128 + c8]);
        const float4 pd1 = *reinterpret_cast<const float4*>(&Pd[(size_t)d * 128 + c8 + 4]);
        float m[8];
        m[0] = (ps0.x + pd0.x) * eav * acc8[i][0];
        m[1] = (ps0.y + pd0.y) * eav * acc8[i][1];
        m[2] = (ps0.z + pd0.z) * eav * acc8[i][2];
        m[3] = (ps0.w + pd0.w) * eav * acc8[i][3];
        m[4] = (ps1.x + pd1.x) * eav * acc8[i][4];
        m[5] = (ps1.y + pd1.y) * eav * acc8[i][5];
        m[6] = (ps1.z + pd1.z) * eav * acc8[i][6];
        m[7] = (ps1.w + pd1.w) * eav * acc8[i][7];
        u32 p0 = pack2(m[0], m[1]), p1 = pack2(m[2], m[3]);
        u32 p2 = pack2(m[4], m[5]), p3 = pack2(m[6], m[7]);
        uint4* o = reinterpret_cast<uint4*>(&MSG[(size_t)row * 128 + c8]);
        *o = make_uint4(p0, p1, p2, p3);
    }
}

// ---------------- MFMA attention + value path ----------------
// Block 256 = 4 waves; tile = 64 edges. GEMM1: [64x128]@[128x256] ([Wa|Wl]),
// wave w owns cols 64w..64w+63. Waves 0,1 -> logits (heads 4w+n); waves 2,3 -> V1.
// GEMM2: V = V1 @ Wv, wave w owns cols 32w..32w+31.
__global__ __launch_bounds__(256) void attn_val_k(
    const u16* __restrict__ MSG, const u16* __restrict__ Wct, const u16* __restrict__ Wvt,
    const float* __restrict__ att_dot, const float* __restrict__ w_int,
    const float* __restrict__ ea,
    float* __restrict__ LG, u16* __restrict__ V, int E) {
    __shared__ __align__(16) u16 V1s[64 * 128];   // XOR-swizzled
    __shared__ __align__(16) u16 Vout[64 * 128];  // plain row-major

    const int tid  = threadIdx.x;
    const int lane = tid & 63;
    const int w    = tid >> 6;
    const int lr   = lane & 15;
    const int lg   = lane >> 4;
    const int e0   = blockIdx.x * 64;

    // ---- GEMM1 ----
    f32x4 acc[4][4];
#pragma unroll
    for (int m = 0; m < 4; ++m)
#pragma unroll
        for (int n = 0; n < 4; ++n) acc[m][n] = (f32x4)(0.0f);

    const int c0w = w * 64;
#pragma unroll
    for (int ks = 0; ks < 4; ++ks) {
        const int kk = lg * 8 + ks * 32;
        bf16x8 a[4], b[4];
#pragma unroll
        for (int m = 0; m < 4; ++m) {
            int r = e0 + lr + 16 * m;
            r = (r < E) ? r : (E - 1);
            a[m] = *reinterpret_cast<const bf16x8*>(&MSG[(size_t)r * 128 + kk]);
        }
#pragma unroll
        for (int n = 0; n < 4; ++n) {
            const int c = c0w + lr + 16 * n;
            b[n] = *reinterpret_cast<const bf16x8*>(&Wct[(size_t)c * 128 + kk]);
        }
#pragma unroll
        for (int m = 0; m < 4; ++m)
#pragma unroll
            for (int n = 0; n < 4; ++n) acc[m][n] = MFMA16(a[m], b[n], acc[m][n]);
    }

    if (w < 2) {
        // logits for heads h = 4w+n: reduce 16 cols across lanes lr=0..15
#pragma unroll
        for (int n = 0; n < 4; ++n) {
            const float ad = att_dot[c0w + 16 * n + lr];
            const int h = 4 * w + n;
#pragma unroll
            for (int m = 0; m < 4; ++m) {
#pragma unroll
                for (int i = 0; i < 4; ++i) {
                    float s = slreluf_(acc[m][n][i]) * ad;
                    s += __shfl_xor(s, 1);
                    s += __shfl_xor(s, 2);
                    s += __shfl_xor(s, 4);
                    s += __shfl_xor(s, 8);
                    if (lr == 0) {
                        const int row = e0 + 16 * m + 4 * lg + i;
                        if (row < E) LG[(size_t)row * 8 + h] = s;
                    }
                }
            }
        }
    } else {
        // V1 = silu(S2)*ea*w_int -> swizzled LDS
#pragma unroll
        for (int n = 0; n < 4; ++n) {
            const int cc = 64 * (w - 2) + 16 * n + lr;
            const float wi = w_int[cc];
#pragma unroll
            for (int m = 0; m < 4; ++m) {
#pragma unroll
                for (int i = 0; i < 4; ++i) {
                    const int r = 16 * m + 4 * lg + i;
                    int row = e0 + r;
                    row = (row < E) ? row : (E - 1);
                    const float v1 = siluf_(acc[m][n][i]) * ea[row] * wi;
                    const int byte = (r * 256 + cc * 2) ^ ((r & 7) << 4);
                    *reinterpret_cast<u16*>(reinterpret_cast<char*>(V1s) + byte) = f2bf(v1);
                }
            }
        }
    }
    __syncthreads();

    // ---- GEMM2: V = V1 @ Wv ----
    f32x4 acc2[4][2];
#pragma unroll
    for (int m = 0; m < 4; ++m)
#pragma unroll
        for (int n = 0; n < 2; ++n) acc2[m][n] = (f32x4)(0.0f);

#pragma unroll
    for (int ks = 0; ks < 4; ++ks) {
        const int kk = lg * 8 + ks * 32;
        bf16x8 a2[4], b2[2];
#pragma unroll
        for (int m = 0; m < 4; ++m) {
            const int r = lr + 16 * m;
            const int byte = (r * 256 + kk * 2) ^ ((r & 7) << 4);
            a2[m] = *reinterpret_cast<const bf16x8*>(reinterpret_cast<const char*>(V1s) + byte);
        }
#pragma unroll
        for (int n = 0; n < 2; ++n) {
            const int j = 32 * w + 16 * n + lr;
            b2[n] = *reinterpret_cast<const bf16x8*>(&Wvt[(size_t)j * 128 + kk]);
        }
#pragma unroll
        for (int m = 0; m < 4; ++m)
#pragma unroll
            for (int n = 0; n < 2; ++n) acc2[m][n] = MFMA16(a2[m], b2[n], acc2[m][n]);
    }

    // store V fragments -> Vout LDS (row-major), then coalesced copy to global
#pragma unroll
    for (int n = 0; n < 2; ++n) {
        const int j = 32 * w + 16 * n + lr;
#pragma unroll
        for (int m = 0; m < 4; ++m)
#pragma unroll
            for (int i = 0; i < 4; ++i) {
                const int r = 16 * m + 4 * lg + i;
                Vout[r * 128 + j] = f2bf(acc2[m][n][i]);
            }
    }
    __syncthreads();

    const uint4* vo = reinterpret_cast<const uint4*>(Vout);
#pragma unroll
    for (int t = 0; t < 4; ++t) {
        const int idx = tid + 256 * t;  // 1024 uint4 = 16 KB
        const int row = idx >> 4;       // 16 uint4 per 128-col row
        if (e0 + row < E)
            *reinterpret_cast<uint4*>(&V[(size_t)e0 * 128 + idx * 8]) = vo[idx];
    }
}

// ---------------- CSR aggregation with exact per-node max subtraction ----------------
__global__ __launch_bounds__(256) void aggregate_k(const int* __restrict__ rowptr,
                                                   const int* __restrict__ eids,
                                                   const float* __restrict__ LG,
                                                   const u16* __restrict__ V,
                                                   float* __restrict__ ACC, int Nn) {
    const int node = blockIdx.x * 4 + (threadIdx.x >> 6);
    const int lane = threadIdx.x & 63;
    if (node >= Nn) return;
    const int s = rowptr[node], t = rowptr[node + 1];
    const int h = lane >> 3;
    float m = -3.4e38f;
    for (int i = s; i < t; ++i) {
        const int e = eids[i];
        m = fmaxf(m, LG[(size_t)e * 8 + h]);
    }
    float a0 = 0.0f, a1 = 0.0f, ds = 0.0f;
    for (int i = s; i < t; ++i) {
        const int e = eids[i];
        const float exv = __expf(LG[(size_t)e * 8 + h] - m);
        const u32 vv = *reinterpret_cast<const u32*>(&V[(size_t)e * 128 + lane * 2]);
        a0 += exv * lo2f(vv);
        a1 += exv * hi2f(vv);
        ds += exv;
    }
    const float inv = 1.0f / (ds + 1e-16f);
    ACC[(size_t)node * 128 + lane * 2]     = a0 * inv;
    ACC[(size_t)node * 128 + lane * 2 + 1] = a1 * inv;
}

// ---------------- launch ----------------
extern "C" void kernel_launch(void* const* d_in, const int* in_sizes, int n_in,
                              void* d_out, int out_size, void* d_ws, size_t ws_size,
                              hipStream_t stream) {
    const float* node_feats = (const float*)d_in[0];
    const float* node_attr  = (const float*)d_in[1];
    const float* edge_attr  = (const float*)d_in[2];
    const float* edge_emb   = (const float*)d_in[3];
    const float* W_src      = (const float*)d_in[4];
    const float* b_src      = (const float*)d_in[5];
    const float* W_dst      = (const float*)d_in[6];
    const float* W_fc1      = (const float*)d_in[7];
    const float* b_fc1      = (const float*)d_in[8];
    const float* W_fc2      = (const float*)d_in[9];
    const float* b_fc2      = (const float*)d_in[10];
    const float* W_fc3      = (const float*)d_in[11];
    const float* W_alpha    = (const float*)d_in[12];
    const float* W_lin      = (const float*)d_in[13];
    const float* w_int      = (const float*)d_in[14];
    const float* W_val      = (const float*)d_in[15];
    const float* att_dot    = (const float*)d_in[16];
    const float* W_out      = (const float*)d_in[17];
    const float* b_out      = (const float*)d_in[18];
    const int* esrc         = (const int*)d_in[19];
    const int* edst         = (const int*)d_in[20];

    const int Nn = in_sizes[0] / 128;  // 30000
    const int E  = in_sizes[19];       // 480000

    char* w = (char*)d_ws;
    auto alloc = [&](size_t bytes) {
        char* p = w;
        w += (bytes + 255) & ~(size_t)255;
        return p;
    };
    u16* MSG = (u16*)alloc((size_t)E * 128 * 2);   // V aliases (per-block RAW-safe)
    u16* V   = MSG;
    float* Psrc = (float*)alloc((size_t)Nn * 128 * 4);
    float* ACC  = Psrc;                            // Psrc dead after radial_msg_k
    float* Pdst = (float*)alloc((size_t)Nn * 128 * 4 > (size_t)E * 8 * 4
                                    ? (size_t)Nn * 128 * 4 : (size_t)E * 8 * 4);
    float* LG   = Pdst;                            // Pdst dead after radial_msg_k
    int* deg    = (int*)alloc((size_t)Nn * 4);
    int* rowptr = (int*)alloc((size_t)(Nn + 1) * 4);
    int* cursor = (int*)alloc((size_t)Nn * 4);
    int* eids   = (int*)alloc((size_t)E * 4);
    u16* Wct    = (u16*)alloc(32768 * 2);          // [256 cols][128 k] bf16
    u16* Wvt    = (u16*)alloc(16384 * 2);          // [128 j][128 c] bf16

    // CSR build + weight prep
    hipMemsetAsync(deg, 0, (size_t)Nn * 4, stream);
    hist_k<<<(E + 255) / 256, 256, 0, stream>>>(edst, deg, E);
    scan_k<<<1, 1024, 0, stream>>>(deg, rowptr, cursor, Nn);
    fill_k<<<(E + 255) / 256, 256, 0, stream>>>(edst, cursor, eids, E);
    prep_w_k<<<192, 256, 0, stream>>>(W_alpha, W_lin, W_val, Wct, Wvt);

    const int nb_node = (Nn + 63) / 64;  // 469
    const int nb_e    = (E + 63) / 64;   // 7500

    gemm_plain_k<128, 128><<<nb_node, 256, 0, stream>>>(node_feats, W_src, b_src, Psrc, Nn);
    gemm_plain_k<128, 128><<<nb_node, 256, 0, stream>>>(node_feats, W_dst, nullptr, Pdst, Nn);

    radial_msg_k<<<nb_e, 256, 0, stream>>>(edge_emb, node_attr, edge_attr, esrc, edst,
                                           W_fc1, b_fc1, W_fc2, b_fc2, W_fc3,
                                           Psrc, Pdst, MSG, E);

    attn_val_k<<<nb_e, 256, 0, stream>>>(MSG, Wct, Wvt, att_dot, w_int, edge_attr, LG, V, E);

    aggregate_k<<<(Nn + 3) / 4, 256, 0, stream>>>(rowptr, eids, LG, V, ACC, Nn);

    gemm_plain_k<128, 128><<<nb_node, 256, 0, stream>>>(ACC, W_out, b_out, (float*)d_out, Nn);
}

// Round 5
// 734.266 us; speedup vs baseline: 3.0828x; 1.9083x over previous
//
#include <hip/hip_runtime.h>
#include <hip/hip_bf16.h>
#include <cstdint>
#include <cstddef>

// GraphAttentionLayer: N=30000, E=480000, C=128, H=8, DH=16, NB=32, NA=16, FC=64.
//
// R5: radial_msg_k rewritten on v_mfma_f32_16x16x32_bf16 (same recipe that took
// attn_val_k 1287us -> off the top-5):
//   - W_fc1/2/3 pre-transposed to bf16 (prep_w_k), read per-lane from global.
//   - fc1 A-operand read directly from global (contiguous 32B per lane slice of
//     [eemb | na[src] | na[dst]]), cvt to bf16 in-register -- no input LDS.
//   - H1/H2/fc3-out through XOR-swizzled LDS (8+8+16 KB; was 101888 B).
//   - Epilogue: per-row float4 Ps/Pd gathers, multiply, bf16 MSG write.
// attn_val_k unchanged from R4 (validated). Exact segment softmax kept.

typedef unsigned short u16;
typedef unsigned int u32;
typedef __attribute__((ext_vector_type(8))) short bf16x8;
typedef __attribute__((ext_vector_type(4))) float f32x4;

union fu_ { float f; u32 u; };
static __device__ __forceinline__ float lo2f(u32 v) { fu_ x; x.u = v << 16; return x.f; }
static __device__ __forceinline__ float hi2f(u32 v) { fu_ x; x.u = v & 0xFFFF0000u; return x.f; }
static __device__ __forceinline__ u16 f2bf(float f) {
    fu_ x; x.f = f;
    u32 r = (x.u + 0x7FFFu + ((x.u >> 16) & 1u)) >> 16;
    return (u16)r;
}
static __device__ __forceinline__ u32 pack2(float a, float b) {
    return (u32)f2bf(a) | ((u32)f2bf(b) << 16);
}
static __device__ __forceinline__ float sigmoidf_(float x) { return 1.0f / (1.0f + __expf(-x)); }
static __device__ __forceinline__ float siluf_(float x)    { return x * sigmoidf_(x); }
static __device__ __forceinline__ float slreluf_(float x)  { return x * (0.2f + 0.8f * sigmoidf_(x)); }

#define MFMA16(a, b, c) __builtin_amdgcn_mfma_f32_16x16x32_bf16((a), (b), (c), 0, 0, 0)

static __device__ __forceinline__ bf16x8 ld8f_bf(const float* __restrict__ p) {
    const float4 x = *reinterpret_cast<const float4*>(p);
    const float4 y = *reinterpret_cast<const float4*>(p + 4);
    bf16x8 r;
    r[0] = (short)f2bf(x.x); r[1] = (short)f2bf(x.y);
    r[2] = (short)f2bf(x.z); r[3] = (short)f2bf(x.w);
    r[4] = (short)f2bf(y.x); r[5] = (short)f2bf(y.y);
    r[6] = (short)f2bf(y.z); r[7] = (short)f2bf(y.w);
    return r;
}

// ---------------- CSR build ----------------
__global__ void hist_k(const int* __restrict__ dst, int* __restrict__ deg, int E) {
    int i = blockIdx.x * blockDim.x + threadIdx.x;
    if (i < E) atomicAdd(&deg[dst[i]], 1);
}

__global__ void scan_k(const int* __restrict__ deg, int* __restrict__ rowptr,
                       int* __restrict__ cursor, int n) {
    __shared__ int part[1024];
    const int t = threadIdx.x;
    const int C = (n + 1023) / 1024;
    const int lo = t * C;
    const int hi = (lo + C < n) ? (lo + C) : n;
    int s = 0;
    for (int i = lo; i < hi; ++i) s += deg[i];
    part[t] = s;
    __syncthreads();
    for (int off = 1; off < 1024; off <<= 1) {
        int v = part[t];
        int u = (t >= off) ? part[t - off] : 0;
        __syncthreads();
        part[t] = v + u;
        __syncthreads();
    }
    int excl = (t == 0) ? 0 : part[t - 1];
    for (int i = lo; i < hi; ++i) {
        rowptr[i] = excl;
        cursor[i] = excl;
        excl += deg[i];
    }
    if (t == 1023) rowptr[n] = part[1023];
}

__global__ void fill_k(const int* __restrict__ dst, int* __restrict__ cursor,
                       int* __restrict__ eids, int E) {
    int i = blockIdx.x * blockDim.x + threadIdx.x;
    if (i < E) {
        int d = dst[i];
        int p = atomicAdd(&cursor[d], 1);
        eids[p] = i;
    }
}

// ---------------- weight prep (all transposed, bf16) ----------------
// Wct[c][k]  = [Wa|Wl]^T   : 256x128
// Wvt[j][c]  = Wv^T        : 128x128
// Bt1[c][k]  = W_fc1^T     : 64x64
// Bt2[c][k]  = W_fc2^T     : 64x64
// Bt3[c][k]  = W_fc3^T     : 128x64
__global__ void prep_w_k(const float* __restrict__ Wa, const float* __restrict__ Wl,
                         const float* __restrict__ Wv,
                         const float* __restrict__ W1, const float* __restrict__ W2,
                         const float* __restrict__ W3,
                         u16* __restrict__ Wct, u16* __restrict__ Wvt,
                         u16* __restrict__ Bt1, u16* __restrict__ Bt2,
                         u16* __restrict__ Bt3) {
    int idx = blockIdx.x * 256 + threadIdx.x;
    if (idx < 32768) {
        int c = idx >> 7, k = idx & 127;
        float v = (c < 128) ? Wa[(size_t)k * 128 + c] : Wl[(size_t)k * 128 + (c - 128)];
        Wct[idx] = f2bf(v);
    } else if (idx < 49152) {
        int t = idx - 32768;
        int j = t >> 7, c = t & 127;
        Wvt[t] = f2bf(Wv[(size_t)c * 128 + j]);
    } else if (idx < 53248) {
        int t = idx - 49152;
        int c = t >> 6, k = t & 63;
        Bt1[t] = f2bf(W1[(size_t)k * 64 + c]);
    } else if (idx < 57344) {
        int t = idx - 53248;
        int c = t >> 6, k = t & 63;
        Bt2[t] = f2bf(W2[(size_t)k * 64 + c]);
    } else if (idx < 65536) {
        int t = idx - 57344;
        int c = t >> 6, k = t & 63;
        Bt3[t] = f2bf(W3[(size_t)k * 128 + c]);
    }
}

// ---------------- node-projection / output GEMM (f32, 64-row tile) ----------------
template <int K, int NC>
__global__ __launch_bounds__(256) void gemm_plain_k(const float* __restrict__ A,
                                                    const float* __restrict__ Bw,
                                                    const float* __restrict__ bias,
                                                    float* __restrict__ Out, int M) {
    constexpr int CT = NC / 16;
    __shared__ __align__(16) float As[K * 68];
    __shared__ __align__(16) float Bs[K * NC];
    const int tid = threadIdx.x;
    const int e0 = blockIdx.x * 64;
    for (int i = tid; i < 64 * K; i += 256) {
        int r = i / K, k = i - r * K;
        int row = e0 + r;
        As[k * 68 + r] = (row < M) ? A[(size_t)row * K + k] : 0.0f;
    }
    for (int i = tid; i < K * NC; i += 256) Bs[i] = Bw[i];
    __syncthreads();

    const int eb = (tid >> 4) * 4;
    const int c0 = (tid & 15) * CT;
    float acc[4][CT];
#pragma unroll
    for (int i = 0; i < 4; ++i)
#pragma unroll
        for (int j = 0; j < CT; ++j) acc[i][j] = 0.0f;

#pragma unroll 4
    for (int k = 0; k < K; ++k) {
        const float4 av = *reinterpret_cast<const float4*>(&As[k * 68 + eb]);
        const float a[4] = {av.x, av.y, av.z, av.w};
#pragma unroll
        for (int jj = 0; jj < CT; jj += 4) {
            const float4 bv = *reinterpret_cast<const float4*>(&Bs[k * NC + c0 + jj]);
            const float b[4] = {bv.x, bv.y, bv.z, bv.w};
#pragma unroll
            for (int j = 0; j < 4; ++j)
#pragma unroll
                for (int i = 0; i < 4; ++i) acc[i][jj + j] += a[i] * b[j];
        }
    }

    float bv[CT];
#pragma unroll
    for (int j = 0; j < CT; ++j) bv[j] = bias ? bias[c0 + j] : 0.0f;
    for (int i = 0; i < 4; ++i) {
        int row = e0 + eb + i;
        if (row >= M) break;
        float o[CT];
#pragma unroll
        for (int j = 0; j < CT; ++j) o[j] = acc[i][j] + bv[j];
        float4* dst4 = reinterpret_cast<float4*>(&Out[(size_t)row * NC + c0]);
        dst4[0] = make_float4(o[0], o[1], o[2], o[3]);
        if (CT == 8) dst4[1] = make_float4(o[4], o[5], o[6], o[7]);
    }
}

// ---------------- MFMA radial MLP + message ----------------
// Block 256 = 4 waves; tile = 64 edges.
// fc1: [64x64]@[64x64]; wave w owns cols 16w..16w+15. A direct from global.
// fc2: same shape, A from H1s (swizzled LDS).
// fc3: [64x64]@[64x128]; wave w owns cols 32w..32w+31.
// Epilogue: MSG = (Ps[src]+Pd[dst])*ea*W, W from Wts LDS.
__global__ __launch_bounds__(256) void radial_msg_k(
    const float* __restrict__ eemb, const float* __restrict__ nattr,
    const float* __restrict__ ea,
    const int* __restrict__ src, const int* __restrict__ dst,
    const u16* __restrict__ Bt1, const float* __restrict__ b1,
    const u16* __restrict__ Bt2, const float* __restrict__ b2,
    const u16* __restrict__ Bt3,
    const float* __restrict__ Ps, const float* __restrict__ Pd,
    u16* __restrict__ MSG, int E) {
    __shared__ __align__(16) u16 H1s[64 * 64];    // swizzled, row stride 128B
    __shared__ __align__(16) u16 H2s[64 * 64];    // swizzled, row stride 128B
    __shared__ __align__(16) u16 Wts[64 * 128];   // swizzled, row stride 256B

    const int tid  = threadIdx.x;
    const int lane = tid & 63;
    const int w    = tid >> 6;
    const int lr   = lane & 15;
    const int lg   = lane >> 4;
    const int e0   = blockIdx.x * 64;

    // ---- fc1: H1 = silu(WF @ W1 + b1) ----
    f32x4 acc1[4];
#pragma unroll
    for (int m = 0; m < 4; ++m) acc1[m] = (f32x4)(0.0f);

#pragma unroll
    for (int ks = 0; ks < 2; ++ks) {
        const int kk = lg * 8 + ks * 32;
        bf16x8 a[4];
#pragma unroll
        for (int m = 0; m < 4; ++m) {
            int row = e0 + lr + 16 * m;
            row = (row < E) ? row : (E - 1);
            const float* ap;
            if (kk < 32)      ap = &eemb[(size_t)row * 32 + kk];
            else if (kk < 48) ap = &nattr[(size_t)src[row] * 16 + (kk - 32)];
            else              ap = &nattr[(size_t)dst[row] * 16 + (kk - 48)];
            a[m] = ld8f_bf(ap);
        }
        const bf16x8 b = *reinterpret_cast<const bf16x8*>(&Bt1[(size_t)(16 * w + lr) * 64 + kk]);
#pragma unroll
        for (int m = 0; m < 4; ++m) acc1[m] = MFMA16(a[m], b, acc1[m]);
    }
    {
        const int c = 16 * w + lr;
        const float bias = b1[c];
#pragma unroll
        for (int m = 0; m < 4; ++m)
#pragma unroll
            for (int i = 0; i < 4; ++i) {
                const int r = 16 * m + 4 * lg + i;
                const int byte = (r * 128 + c * 2) ^ ((r & 7) << 4);
                *reinterpret_cast<u16*>(reinterpret_cast<char*>(H1s) + byte) =
                    f2bf(siluf_(acc1[m][i] + bias));
            }
    }
    __syncthreads();

    // ---- fc2: H2 = silu(H1 @ W2 + b2) ----
    f32x4 acc2[4];
#pragma unroll
    for (int m = 0; m < 4; ++m) acc2[m] = (f32x4)(0.0f);

#pragma unroll
    for (int ks = 0; ks < 2; ++ks) {
        const int kk = lg * 8 + ks * 32;
        bf16x8 a[4];
#pragma unroll
        for (int m = 0; m < 4; ++m) {
            const int r = lr + 16 * m;
            const int byte = (r * 128 + kk * 2) ^ ((r & 7) << 4);
            a[m] = *reinterpret_cast<const bf16x8*>(reinterpret_cast<const char*>(H1s) + byte);
        }
        const bf16x8 b = *reinterpret_cast<const bf16x8*>(&Bt2[(size_t)(16 * w + lr) * 64 + kk]);
#pragma unroll
        for (int m = 0; m < 4; ++m) acc2[m] = MFMA16(a[m], b, acc2[m]);
    }
    {
        const int c = 16 * w + lr;
        const float bias = b2[c];
#pragma unroll
        for (int m = 0; m < 4; ++m)
#pragma unroll
            for (int i = 0; i < 4; ++i) {
                const int r = 16 * m + 4 * lg + i;
                const int byte = (r * 128 + c * 2) ^ ((r & 7) << 4);
                *reinterpret_cast<u16*>(reinterpret_cast<char*>(H2s) + byte) =
                    f2bf(siluf_(acc2[m][i] + bias));
            }
    }
    __syncthreads();

    // ---- fc3: W = H2 @ W3 ----
    f32x4 acc3[2][4];
#pragma unroll
    for (int n = 0; n < 2; ++n)
#pragma unroll
        for (int m = 0; m < 4; ++m) acc3[n][m] = (f32x4)(0.0f);

#pragma unroll
    for (int ks = 0; ks < 2; ++ks) {
        const int kk = lg * 8 + ks * 32;
        bf16x8 a[4];
#pragma unroll
        for (int m = 0; m < 4; ++m) {
            const int r = lr + 16 * m;
            const int byte = (r * 128 + kk * 2) ^ ((r & 7) << 4);
            a[m] = *reinterpret_cast<const bf16x8*>(reinterpret_cast<const char*>(H2s) + byte);
        }
        bf16x8 b[2];
#pragma unroll
        for (int n = 0; n < 2; ++n) {
            const int c = 32 * w + 16 * n + lr;
            b[n] = *reinterpret_cast<const bf16x8*>(&Bt3[(size_t)c * 64 + kk]);
        }
#pragma unroll
        for (int n = 0; n < 2; ++n)
#pragma unroll
            for (int m = 0; m < 4; ++m) acc3[n][m] = MFMA16(a[m], b[n], acc3[n][m]);
    }
#pragma unroll
    for (int n = 0; n < 2; ++n) {
        const int c = 32 * w + 16 * n + lr;
#pragma unroll
        for (int m = 0; m < 4; ++m)
#pragma unroll
            for (int i = 0; i < 4; ++i) {
                const int r = 16 * m + 4 * lg + i;
                const int byte = (r * 256 + c * 2) ^ ((r & 7) << 4);
                *reinterpret_cast<u16*>(reinterpret_cast<char*>(Wts) + byte) =
                    f2bf(acc3[n][m][i]);
            }
    }
    __syncthreads();

    // ---- epilogue: MSG = (Ps[src]+Pd[dst]) * ea * W ----
#pragma unroll
    for (int t = 0; t < 4; ++t) {
        const int idx = tid + 256 * t;  // 0..1023: 64 rows x 16 8-col chunks
        const int r = idx >> 4;
        const int c8 = (idx & 15) * 8;
        const int row = e0 + r;
        if (row >= E) continue;
        const int byte = (r * 256 + c8 * 2) ^ ((r & 7) << 4);
        const uint4 wv = *reinterpret_cast<const uint4*>(reinterpret_cast<const char*>(Wts) + byte);
        const float wt[8] = {lo2f(wv.x), hi2f(wv.x), lo2f(wv.y), hi2f(wv.y),
                             lo2f(wv.z), hi2f(wv.z), lo2f(wv.w), hi2f(wv.w)};
        const int s = src[row], d = dst[row];
        const float eav = ea[row];
        const float4 ps0 = *reinterpret_cast<const float4*>(&Ps[(size_t)s * 128 + c8]);
        const float4 ps1 = *reinterpret_cast<const float4*>(&Ps[(size_t)s * 128 + c8 + 4]);
        const float4 pd0 = *reinterpret_cast<const float4*>(&Pd[(size_t)d * 128 + c8]);
        const float4 pd1 = *reinterpret_cast<const float4*>(&Pd[(size_t)d * 128 + c8 + 4]);
        float m[8];
        m[0] = (ps0.x + pd0.x) * eav * wt[0];
        m[1] = (ps0.y + pd0.y) * eav * wt[1];
        m[2] = (ps0.z + pd0.z) * eav * wt[2];
        m[3] = (ps0.w + pd0.w) * eav * wt[3];
        m[4] = (ps1.x + pd1.x) * eav * wt[4];
        m[5] = (ps1.y + pd1.y) * eav * wt[5];
        m[6] = (ps1.z + pd1.z) * eav * wt[6];
        m[7] = (ps1.w + pd1.w) * eav * wt[7];
        u32 p0 = pack2(m[0], m[1]), p1 = pack2(m[2], m[3]);
        u32 p2 = pack2(m[4], m[5]), p3 = pack2(m[6], m[7]);
        *reinterpret_cast<uint4*>(&MSG[(size_t)row * 128 + c8]) = make_uint4(p0, p1, p2, p3);
    }
}

// ---------------- MFMA attention + value path (unchanged from R4) ----------------
__global__ __launch_bounds__(256) void attn_val_k(
    const u16* __restrict__ MSG, const u16* __restrict__ Wct, const u16* __restrict__ Wvt,
    const float* __restrict__ att_dot, const float* __restrict__ w_int,
    const float* __restrict__ ea,
    float* __restrict__ LG, u16* __restrict__ V, int E) {
    __shared__ __align__(16) u16 V1s[64 * 128];   // XOR-swizzled
    __shared__ __align__(16) u16 Vout[64 * 128];  // plain row-major

    const int tid  = threadIdx.x;
    const int lane = tid & 63;
    const int w    = tid >> 6;
    const int lr   = lane & 15;
    const int lg   = lane >> 4;
    const int e0   = blockIdx.x * 64;

    // ---- GEMM1 ----
    f32x4 acc[4][4];
#pragma unroll
    for (int m = 0; m < 4; ++m)
#pragma unroll
        for (int n = 0; n < 4; ++n) acc[m][n] = (f32x4)(0.0f);

    const int c0w = w * 64;
#pragma unroll
    for (int ks = 0; ks < 4; ++ks) {
        const int kk = lg * 8 + ks * 32;
        bf16x8 a[4], b[4];
#pragma unroll
        for (int m = 0; m < 4; ++m) {
            int r = e0 + lr + 16 * m;
            r = (r < E) ? r : (E - 1);
            a[m] = *reinterpret_cast<const bf16x8*>(&MSG[(size_t)r * 128 + kk]);
        }
#pragma unroll
        for (int n = 0; n < 4; ++n) {
            const int c = c0w + lr + 16 * n;
            b[n] = *reinterpret_cast<const bf16x8*>(&Wct[(size_t)c * 128 + kk]);
        }
#pragma unroll
        for (int m = 0; m < 4; ++m)
#pragma unroll
            for (int n = 0; n < 4; ++n) acc[m][n] = MFMA16(a[m], b[n], acc[m][n]);
    }

    if (w < 2) {
#pragma unroll
        for (int n = 0; n < 4; ++n) {
            const float ad = att_dot[c0w + 16 * n + lr];
            const int h = 4 * w + n;
#pragma unroll
            for (int m = 0; m < 4; ++m) {
#pragma unroll
                for (int i = 0; i < 4; ++i) {
                    float s = slreluf_(acc[m][n][i]) * ad;
                    s += __shfl_xor(s, 1);
                    s += __shfl_xor(s, 2);
                    s += __shfl_xor(s, 4);
                    s += __shfl_xor(s, 8);
                    if (lr == 0) {
                        const int row = e0 + 16 * m + 4 * lg + i;
                        if (row < E) LG[(size_t)row * 8 + h] = s;
                    }
                }
            }
        }
    } else {
#pragma unroll
        for (int n = 0; n < 4; ++n) {
            const int cc = 64 * (w - 2) + 16 * n + lr;
            const float wi = w_int[cc];
#pragma unroll
            for (int m = 0; m < 4; ++m) {
#pragma unroll
                for (int i = 0; i < 4; ++i) {
                    const int r = 16 * m + 4 * lg + i;
                    int row = e0 + r;
                    row = (row < E) ? row : (E - 1);
                    const float v1 = siluf_(acc[m][n][i]) * ea[row] * wi;
                    const int byte = (r * 256 + cc * 2) ^ ((r & 7) << 4);
                    *reinterpret_cast<u16*>(reinterpret_cast<char*>(V1s) + byte) = f2bf(v1);
                }
            }
        }
    }
    __syncthreads();

    // ---- GEMM2: V = V1 @ Wv ----
    f32x4 acc2[4][2];
#pragma unroll
    for (int m = 0; m < 4; ++m)
#pragma unroll
        for (int n = 0; n < 2; ++n) acc2[m][n] = (f32x4)(0.0f);

#pragma unroll
    for (int ks = 0; ks < 4; ++ks) {
        const int kk = lg * 8 + ks * 32;
        bf16x8 a2[4], b2[2];
#pragma unroll
        for (int m = 0; m < 4; ++m) {
            const int r = lr + 16 * m;
            const int byte = (r * 256 + kk * 2) ^ ((r & 7) << 4);
            a2[m] = *reinterpret_cast<const bf16x8*>(reinterpret_cast<const char*>(V1s) + byte);
        }
#pragma unroll
        for (int n = 0; n < 2; ++n) {
            const int j = 32 * w + 16 * n + lr;
            b2[n] = *reinterpret_cast<const bf16x8*>(&Wvt[(size_t)j * 128 + kk]);
        }
#pragma unroll
        for (int m = 0; m < 4; ++m)
#pragma unroll
            for (int n = 0; n < 2; ++n) acc2[m][n] = MFMA16(a2[m], b2[n], acc2[m][n]);
    }

#pragma unroll
    for (int n = 0; n < 2; ++n) {
        const int j = 32 * w + 16 * n + lr;
#pragma unroll
        for (int m = 0; m < 4; ++m)
#pragma unroll
            for (int i = 0; i < 4; ++i) {
                const int r = 16 * m + 4 * lg + i;
                Vout[r * 128 + j] = f2bf(acc2[m][n][i]);
            }
    }
    __syncthreads();

    const uint4* vo = reinterpret_cast<const uint4*>(Vout);
#pragma unroll
    for (int t = 0; t < 4; ++t) {
        const int idx = tid + 256 * t;
        const int row = idx >> 4;
        if (e0 + row < E)
            *reinterpret_cast<uint4*>(&V[(size_t)e0 * 128 + idx * 8]) = vo[idx];
    }
}

// ---------------- CSR aggregation with exact per-node max subtraction ----------------
__global__ __launch_bounds__(256) void aggregate_k(const int* __restrict__ rowptr,
                                                   const int* __restrict__ eids,
                                                   const float* __restrict__ LG,
                                                   const u16* __restrict__ V,
                                                   float* __restrict__ ACC, int Nn) {
    const int node = blockIdx.x * 4 + (threadIdx.x >> 6);
    const int lane = threadIdx.x & 63;
    if (node >= Nn) return;
    const int s = rowptr[node], t = rowptr[node + 1];
    const int h = lane >> 3;
    float m = -3.4e38f;
    for (int i = s; i < t; ++i) {
        const int e = eids[i];
        m = fmaxf(m, LG[(size_t)e * 8 + h]);
    }
    float a0 = 0.0f, a1 = 0.0f, ds = 0.0f;
    for (int i = s; i < t; ++i) {
        const int e = eids[i];
        const float exv = __expf(LG[(size_t)e * 8 + h] - m);
        const u32 vv = *reinterpret_cast<const u32*>(&V[(size_t)e * 128 + lane * 2]);
        a0 += exv * lo2f(vv);
        a1 += exv * hi2f(vv);
        ds += exv;
    }
    const float inv = 1.0f / (ds + 1e-16f);
    ACC[(size_t)node * 128 + lane * 2]     = a0 * inv;
    ACC[(size_t)node * 128 + lane * 2 + 1] = a1 * inv;
}

// ---------------- launch ----------------
extern "C" void kernel_launch(void* const* d_in, const int* in_sizes, int n_in,
                              void* d_out, int out_size, void* d_ws, size_t ws_size,
                              hipStream_t stream) {
    const float* node_feats = (const float*)d_in[0];
    const float* node_attr  = (const float*)d_in[1];
    const float* edge_attr  = (const float*)d_in[2];
    const float* edge_emb   = (const float*)d_in[3];
    const float* W_src      = (const float*)d_in[4];
    const float* b_src      = (const float*)d_in[5];
    const float* W_dst      = (const float*)d_in[6];
    const float* W_fc1      = (const float*)d_in[7];
    const float* b_fc1      = (const float*)d_in[8];
    const float* W_fc2      = (const float*)d_in[9];
    const float* b_fc2      = (const float*)d_in[10];
    const float* W_fc3      = (const float*)d_in[11];
    const float* W_alpha    = (const float*)d_in[12];
    const float* W_lin      = (const float*)d_in[13];
    const float* w_int      = (const float*)d_in[14];
    const float* W_val      = (const float*)d_in[15];
    const float* att_dot    = (const float*)d_in[16];
    const float* W_out      = (const float*)d_in[17];
    const float* b_out      = (const float*)d_in[18];
    const int* esrc         = (const int*)d_in[19];
    const int* edst         = (const int*)d_in[20];

    const int Nn = in_sizes[0] / 128;  // 30000
    const int E  = in_sizes[19];       // 480000

    char* w = (char*)d_ws;
    auto alloc = [&](size_t bytes) {
        char* p = w;
        w += (bytes + 255) & ~(size_t)255;
        return p;
    };
    u16* MSG = (u16*)alloc((size_t)E * 128 * 2);   // V aliases (per-block RAW-safe)
    u16* V   = MSG;
    float* Psrc = (float*)alloc((size_t)Nn * 128 * 4);
    float* ACC  = Psrc;                            // Psrc dead after radial_msg_k
    float* Pdst = (float*)alloc((size_t)Nn * 128 * 4 > (size_t)E * 8 * 4
                                    ? (size_t)Nn * 128 * 4 : (size_t)E * 8 * 4);
    float* LG   = Pdst;                            // Pdst dead after radial_msg_k
    int* deg    = (int*)alloc((size_t)Nn * 4);
    int* rowptr = (int*)alloc((size_t)(Nn + 1) * 4);
    int* cursor = (int*)alloc((size_t)Nn * 4);
    int* eids   = (int*)alloc((size_t)E * 4);
    u16* Wct    = (u16*)alloc(32768 * 2);          // [256 c][128 k]
    u16* Wvt    = (u16*)alloc(16384 * 2);          // [128 j][128 c]
    u16* Bt1    = (u16*)alloc(4096 * 2);           // [64 c][64 k]
    u16* Bt2    = (u16*)alloc(4096 * 2);
    u16* Bt3    = (u16*)alloc(8192 * 2);           // [128 c][64 k]

    // CSR build + weight prep
    hipMemsetAsync(deg, 0, (size_t)Nn * 4, stream);
    hist_k<<<(E + 255) / 256, 256, 0, stream>>>(edst, deg, E);
    scan_k<<<1, 1024, 0, stream>>>(deg, rowptr, cursor, Nn);
    fill_k<<<(E + 255) / 256, 256, 0, stream>>>(edst, cursor, eids, E);
    prep_w_k<<<256, 256, 0, stream>>>(W_alpha, W_lin, W_val, W_fc1, W_fc2, W_fc3,
                                      Wct, Wvt, Bt1, Bt2, Bt3);

    const int nb_node = (Nn + 63) / 64;  // 469
    const int nb_e    = (E + 63) / 64;   // 7500

    gemm_plain_k<128, 128><<<nb_node, 256, 0, stream>>>(node_feats, W_src, b_src, Psrc, Nn);
    gemm_plain_k<128, 128><<<nb_node, 256, 0, stream>>>(node_feats, W_dst, nullptr, Pdst, Nn);

    radial_msg_k<<<nb_e, 256, 0, stream>>>(edge_emb, node_attr, edge_attr, esrc, edst,
                                           Bt1, b_fc1, Bt2, b_fc2, Bt3,
                                           Psrc, Pdst, MSG, E);

    attn_val_k<<<nb_e, 256, 0, stream>>>(MSG, Wct, Wvt, att_dot, w_int, edge_attr, LG, V, E);

    aggregate_k<<<(Nn + 3) / 4, 256, 0, stream>>>(rowptr, eids, LG, V, ACC, Nn);

    gemm_plain_k<128, 128><<<nb_node, 256, 0, stream>>>(ACC, W_out, b_out, (float*)d_out, Nn);
}

// Round 6
// 721.333 us; speedup vs baseline: 3.1380x; 1.0179x over previous
//
#include <hip/hip_runtime.h>
#include <hip/hip_bf16.h>
#include <cstdint>
#include <cstddef>

// GraphAttentionLayer: N=30000, E=480000, C=128, H=8, DH=16, NB=32, NA=16, FC=64.
//
// R6: radial_msg_k + attn_val_k fused into msg_attn_k. The MSG [E,128] tensor
// never touches HBM: each 64-edge tile computes fc1/fc2/fc3 + message epilogue
// into LDS, then runs the attention/value GEMMs straight off that LDS tile.
// LDS regions are reused along the dataflow (51200 B total -> 3 blocks/CU):
//   region A [0,16K):    H1s(8K)+H2s(8K)  -> V1s (after fc3)
//   region B [16K,32K):  Wts              -> Vout (after epilogue)
//   region C [32K,48K):  MSGs
//   region D [48K,50K):  LG staging (64x8 f32), coalesced f32x4 writeout
// All swizzles: byte ^= (row&7)<<4 at 16B granularity, write==read involution.
// Exact segment softmax kept: LG stored, max-sub in aggregate_k.

typedef unsigned short u16;
typedef unsigned int u32;
typedef __attribute__((ext_vector_type(8))) short bf16x8;
typedef __attribute__((ext_vector_type(4))) float f32x4;

union fu_ { float f; u32 u; };
static __device__ __forceinline__ float lo2f(u32 v) { fu_ x; x.u = v << 16; return x.f; }
static __device__ __forceinline__ float hi2f(u32 v) { fu_ x; x.u = v & 0xFFFF0000u; return x.f; }
static __device__ __forceinline__ u16 f2bf(float f) {
    fu_ x; x.f = f;
    u32 r = (x.u + 0x7FFFu + ((x.u >> 16) & 1u)) >> 16;
    return (u16)r;
}
static __device__ __forceinline__ u32 pack2(float a, float b) {
    return (u32)f2bf(a) | ((u32)f2bf(b) << 16);
}
static __device__ __forceinline__ float sigmoidf_(float x) { return 1.0f / (1.0f + __expf(-x)); }
static __device__ __forceinline__ float siluf_(float x)    { return x * sigmoidf_(x); }
static __device__ __forceinline__ float slreluf_(float x)  { return x * (0.2f + 0.8f * sigmoidf_(x)); }

#define MFMA16(a, b, c) __builtin_amdgcn_mfma_f32_16x16x32_bf16((a), (b), (c), 0, 0, 0)

static __device__ __forceinline__ bf16x8 ld8f_bf(const float* __restrict__ p) {
    const float4 x = *reinterpret_cast<const float4*>(p);
    const float4 y = *reinterpret_cast<const float4*>(p + 4);
    bf16x8 r;
    r[0] = (short)f2bf(x.x); r[1] = (short)f2bf(x.y);
    r[2] = (short)f2bf(x.z); r[3] = (short)f2bf(x.w);
    r[4] = (short)f2bf(y.x); r[5] = (short)f2bf(y.y);
    r[6] = (short)f2bf(y.z); r[7] = (short)f2bf(y.w);
    return r;
}

// ---------------- CSR build ----------------
__global__ void hist_k(const int* __restrict__ dst, int* __restrict__ deg, int E) {
    int i = blockIdx.x * blockDim.x + threadIdx.x;
    if (i < E) atomicAdd(&deg[dst[i]], 1);
}

__global__ void scan_k(const int* __restrict__ deg, int* __restrict__ rowptr,
                       int* __restrict__ cursor, int n) {
    __shared__ int part[1024];
    const int t = threadIdx.x;
    const int C = (n + 1023) / 1024;
    const int lo = t * C;
    const int hi = (lo + C < n) ? (lo + C) : n;
    int s = 0;
    for (int i = lo; i < hi; ++i) s += deg[i];
    part[t] = s;
    __syncthreads();
    for (int off = 1; off < 1024; off <<= 1) {
        int v = part[t];
        int u = (t >= off) ? part[t - off] : 0;
        __syncthreads();
        part[t] = v + u;
        __syncthreads();
    }
    int excl = (t == 0) ? 0 : part[t - 1];
    for (int i = lo; i < hi; ++i) {
        rowptr[i] = excl;
        cursor[i] = excl;
        excl += deg[i];
    }
    if (t == 1023) rowptr[n] = part[1023];
}

__global__ void fill_k(const int* __restrict__ dst, int* __restrict__ cursor,
                       int* __restrict__ eids, int E) {
    int i = blockIdx.x * blockDim.x + threadIdx.x;
    if (i < E) {
        int d = dst[i];
        int p = atomicAdd(&cursor[d], 1);
        eids[p] = i;
    }
}

// ---------------- weight prep (all transposed, bf16) ----------------
__global__ void prep_w_k(const float* __restrict__ Wa, const float* __restrict__ Wl,
                         const float* __restrict__ Wv,
                         const float* __restrict__ W1, const float* __restrict__ W2,
                         const float* __restrict__ W3,
                         u16* __restrict__ Wct, u16* __restrict__ Wvt,
                         u16* __restrict__ Bt1, u16* __restrict__ Bt2,
                         u16* __restrict__ Bt3) {
    int idx = blockIdx.x * 256 + threadIdx.x;
    if (idx < 32768) {
        int c = idx >> 7, k = idx & 127;
        float v = (c < 128) ? Wa[(size_t)k * 128 + c] : Wl[(size_t)k * 128 + (c - 128)];
        Wct[idx] = f2bf(v);
    } else if (idx < 49152) {
        int t = idx - 32768;
        int j = t >> 7, c = t & 127;
        Wvt[t] = f2bf(Wv[(size_t)c * 128 + j]);
    } else if (idx < 53248) {
        int t = idx - 49152;
        int c = t >> 6, k = t & 63;
        Bt1[t] = f2bf(W1[(size_t)k * 64 + c]);
    } else if (idx < 57344) {
        int t = idx - 53248;
        int c = t >> 6, k = t & 63;
        Bt2[t] = f2bf(W2[(size_t)k * 64 + c]);
    } else if (idx < 65536) {
        int t = idx - 57344;
        int c = t >> 6, k = t & 63;
        Bt3[t] = f2bf(W3[(size_t)k * 128 + c]);
    }
}

// ---------------- node-projection / output GEMM (f32, 64-row tile) ----------------
template <int K, int NC>
__global__ __launch_bounds__(256) void gemm_plain_k(const float* __restrict__ A,
                                                    const float* __restrict__ Bw,
                                                    const float* __restrict__ bias,
                                                    float* __restrict__ Out, int M) {
    constexpr int CT = NC / 16;
    __shared__ __align__(16) float As[K * 68];
    __shared__ __align__(16) float Bs[K * NC];
    const int tid = threadIdx.x;
    const int e0 = blockIdx.x * 64;
    for (int i = tid; i < 64 * K; i += 256) {
        int r = i / K, k = i - r * K;
        int row = e0 + r;
        As[k * 68 + r] = (row < M) ? A[(size_t)row * K + k] : 0.0f;
    }
    for (int i = tid; i < K * NC; i += 256) Bs[i] = Bw[i];
    __syncthreads();

    const int eb = (tid >> 4) * 4;
    const int c0 = (tid & 15) * CT;
    float acc[4][CT];
#pragma unroll
    for (int i = 0; i < 4; ++i)
#pragma unroll
        for (int j = 0; j < CT; ++j) acc[i][j] = 0.0f;

#pragma unroll 4
    for (int k = 0; k < K; ++k) {
        const float4 av = *reinterpret_cast<const float4*>(&As[k * 68 + eb]);
        const float a[4] = {av.x, av.y, av.z, av.w};
#pragma unroll
        for (int jj = 0; jj < CT; jj += 4) {
            const float4 bv = *reinterpret_cast<const float4*>(&Bs[k * NC + c0 + jj]);
            const float b[4] = {bv.x, bv.y, bv.z, bv.w};
#pragma unroll
            for (int j = 0; j < 4; ++j)
#pragma unroll
                for (int i = 0; i < 4; ++i) acc[i][jj + j] += a[i] * b[j];
        }
    }

    float bv[CT];
#pragma unroll
    for (int j = 0; j < CT; ++j) bv[j] = bias ? bias[c0 + j] : 0.0f;
    for (int i = 0; i < 4; ++i) {
        int row = e0 + eb + i;
        if (row >= M) break;
        float o[CT];
#pragma unroll
        for (int j = 0; j < CT; ++j) o[j] = acc[i][j] + bv[j];
        float4* dst4 = reinterpret_cast<float4*>(&Out[(size_t)row * NC + c0]);
        dst4[0] = make_float4(o[0], o[1], o[2], o[3]);
        if (CT == 8) dst4[1] = make_float4(o[4], o[5], o[6], o[7]);
    }
}

// ---------------- fused radial MLP + message + attention + value ----------------
// Block 256 = 4 waves; tile = 64 edges; MSG lives only in LDS.
__global__ __launch_bounds__(256) void msg_attn_k(
    const float* __restrict__ eemb, const float* __restrict__ nattr,
    const float* __restrict__ ea,
    const int* __restrict__ src, const int* __restrict__ dst,
    const u16* __restrict__ Bt1, const float* __restrict__ b1,
    const u16* __restrict__ Bt2, const float* __restrict__ b2,
    const u16* __restrict__ Bt3,
    const float* __restrict__ Ps, const float* __restrict__ Pd,
    const u16* __restrict__ Wct, const u16* __restrict__ Wvt,
    const float* __restrict__ att_dot, const float* __restrict__ w_int,
    float* __restrict__ LG, u16* __restrict__ V, int E) {
    __shared__ __align__(16) char smem[51200];
    char* regA  = smem;           // H1s [0,8K) + H2s [8K,16K); later V1s (16K)
    char* regB  = smem + 16384;   // Wts (16K); later Vout (16K)
    char* regC  = smem + 32768;   // MSGs (16K)
    float* lgs  = (float*)(smem + 49152);  // 64*8 f32

    const int tid  = threadIdx.x;
    const int lane = tid & 63;
    const int w    = tid >> 6;
    const int lr   = lane & 15;
    const int lg   = lane >> 4;
    const int e0   = blockIdx.x * 64;

    // ---- phase 1: fc1  H1 = silu(WF @ W1 + b1), A direct from global ----
    {
        f32x4 acc1[4];
#pragma unroll
        for (int m = 0; m < 4; ++m) acc1[m] = (f32x4)(0.0f);
#pragma unroll
        for (int ks = 0; ks < 2; ++ks) {
            const int kk = lg * 8 + ks * 32;
            bf16x8 a[4];
#pragma unroll
            for (int m = 0; m < 4; ++m) {
                int row = e0 + lr + 16 * m;
                row = (row < E) ? row : (E - 1);
                const float* ap;
                if (kk < 32)      ap = &eemb[(size_t)row * 32 + kk];
                else if (kk < 48) ap = &nattr[(size_t)src[row] * 16 + (kk - 32)];
                else              ap = &nattr[(size_t)dst[row] * 16 + (kk - 48)];
                a[m] = ld8f_bf(ap);
            }
            const bf16x8 b = *reinterpret_cast<const bf16x8*>(&Bt1[(size_t)(16 * w + lr) * 64 + kk]);
#pragma unroll
            for (int m = 0; m < 4; ++m) acc1[m] = MFMA16(a[m], b, acc1[m]);
        }
        const int c = 16 * w + lr;
        const float bias = b1[c];
#pragma unroll
        for (int m = 0; m < 4; ++m)
#pragma unroll
            for (int i = 0; i < 4; ++i) {
                const int r = 16 * m + 4 * lg + i;
                const int byte = (r * 128 + c * 2) ^ ((r & 7) << 4);
                *reinterpret_cast<u16*>(regA + byte) = f2bf(siluf_(acc1[m][i] + bias));
            }
    }
    __syncthreads();

    // ---- phase 2: fc2  H2 = silu(H1 @ W2 + b2) ----
    {
        f32x4 acc2[4];
#pragma unroll
        for (int m = 0; m < 4; ++m) acc2[m] = (f32x4)(0.0f);
#pragma unroll
        for (int ks = 0; ks < 2; ++ks) {
            const int kk = lg * 8 + ks * 32;
            bf16x8 a[4];
#pragma unroll
            for (int m = 0; m < 4; ++m) {
                const int r = lr + 16 * m;
                const int byte = (r * 128 + kk * 2) ^ ((r & 7) << 4);
                a[m] = *reinterpret_cast<const bf16x8*>(regA + byte);
            }
            const bf16x8 b = *reinterpret_cast<const bf16x8*>(&Bt2[(size_t)(16 * w + lr) * 64 + kk]);
#pragma unroll
            for (int m = 0; m < 4; ++m) acc2[m] = MFMA16(a[m], b, acc2[m]);
        }
        const int c = 16 * w + lr;
        const float bias = b2[c];
#pragma unroll
        for (int m = 0; m < 4; ++m)
#pragma unroll
            for (int i = 0; i < 4; ++i) {
                const int r = 16 * m + 4 * lg + i;
                const int byte = (r * 128 + c * 2) ^ ((r & 7) << 4);
                *reinterpret_cast<u16*>(regA + 8192 + byte) = f2bf(siluf_(acc2[m][i] + bias));
            }
    }
    __syncthreads();

    // ---- phase 3: fc3  W = H2 @ W3 -> Wts ----
    {
        f32x4 acc3[2][4];
#pragma unroll
        for (int n = 0; n < 2; ++n)
#pragma unroll
            for (int m = 0; m < 4; ++m) acc3[n][m] = (f32x4)(0.0f);
#pragma unroll
        for (int ks = 0; ks < 2; ++ks) {
            const int kk = lg * 8 + ks * 32;
            bf16x8 a[4];
#pragma unroll
            for (int m = 0; m < 4; ++m) {
                const int r = lr + 16 * m;
                const int byte = (r * 128 + kk * 2) ^ ((r & 7) << 4);
                a[m] = *reinterpret_cast<const bf16x8*>(regA + 8192 + byte);
            }
            bf16x8 b[2];
#pragma unroll
            for (int n = 0; n < 2; ++n) {
                const int c = 32 * w + 16 * n + lr;
                b[n] = *reinterpret_cast<const bf16x8*>(&Bt3[(size_t)c * 64 + kk]);
            }
#pragma unroll
            for (int n = 0; n < 2; ++n)
#pragma unroll
                for (int m = 0; m < 4; ++m) acc3[n][m] = MFMA16(a[m], b[n], acc3[n][m]);
        }
#pragma unroll
        for (int n = 0; n < 2; ++n) {
            const int c = 32 * w + 16 * n + lr;
#pragma unroll
            for (int m = 0; m < 4; ++m)
#pragma unroll
                for (int i = 0; i < 4; ++i) {
                    const int r = 16 * m + 4 * lg + i;
                    const int byte = (r * 256 + c * 2) ^ ((r & 7) << 4);
                    *reinterpret_cast<u16*>(regB + byte) = f2bf(acc3[n][m][i]);
                }
        }
    }
    __syncthreads();

    // ---- phase 4: epilogue  MSG = (Ps[src]+Pd[dst]) * ea * W -> MSGs (LDS only) ----
#pragma unroll
    for (int t = 0; t < 4; ++t) {
        const int idx = tid + 256 * t;  // 64 rows x 16 chunks of 8 cols
        const int r = idx >> 4;
        const int c8 = (idx & 15) * 8;
        const int row = e0 + r;
        if (row >= E) continue;
        const int byte = (r * 256 + c8 * 2) ^ ((r & 7) << 4);
        const uint4 wv = *reinterpret_cast<const uint4*>(regB + byte);
        const float wt[8] = {lo2f(wv.x), hi2f(wv.x), lo2f(wv.y), hi2f(wv.y),
                             lo2f(wv.z), hi2f(wv.z), lo2f(wv.w), hi2f(wv.w)};
        const int s = src[row], d = dst[row];
        const float eav = ea[row];
        const float4 ps0 = *reinterpret_cast<const float4*>(&Ps[(size_t)s * 128 + c8]);
        const float4 ps1 = *reinterpret_cast<const float4*>(&Ps[(size_t)s * 128 + c8 + 4]);
        const float4 pd0 = *reinterpret_cast<const float4*>(&Pd[(size_t)d * 128 + c8]);
        const float4 pd1 = *reinterpret_cast<const float4*>(&Pd[(size_t)d * 128 + c8 + 4]);
        float m[8];
        m[0] = (ps0.x + pd0.x) * eav * wt[0];
        m[1] = (ps0.y + pd0.y) * eav * wt[1];
        m[2] = (ps0.z + pd0.z) * eav * wt[2];
        m[3] = (ps0.w + pd0.w) * eav * wt[3];
        m[4] = (ps1.x + pd1.x) * eav * wt[4];
        m[5] = (ps1.y + pd1.y) * eav * wt[5];
        m[6] = (ps1.z + pd1.z) * eav * wt[6];
        m[7] = (ps1.w + pd1.w) * eav * wt[7];
        u32 p0 = pack2(m[0], m[1]), p1 = pack2(m[2], m[3]);
        u32 p2 = pack2(m[4], m[5]), p3 = pack2(m[6], m[7]);
        *reinterpret_cast<uint4*>(regC + byte) = make_uint4(p0, p1, p2, p3);
    }
    __syncthreads();

    // ---- phase 5: GEMM1  scores|v1pre = MSG @ [Wa|Wl], A from MSGs LDS ----
    f32x4 acc[4][4];
#pragma unroll
    for (int m = 0; m < 4; ++m)
#pragma unroll
        for (int n = 0; n < 4; ++n) acc[m][n] = (f32x4)(0.0f);

    const int c0w = w * 64;
#pragma unroll
    for (int ks = 0; ks < 4; ++ks) {
        const int kk = lg * 8 + ks * 32;
        bf16x8 a[4], b[4];
#pragma unroll
        for (int m = 0; m < 4; ++m) {
            const int r = lr + 16 * m;
            const int byte = (r * 256 + kk * 2) ^ ((r & 7) << 4);
            a[m] = *reinterpret_cast<const bf16x8*>(regC + byte);
        }
#pragma unroll
        for (int n = 0; n < 4; ++n) {
            const int c = c0w + lr + 16 * n;
            b[n] = *reinterpret_cast<const bf16x8*>(&Wct[(size_t)c * 128 + kk]);
        }
#pragma unroll
        for (int m = 0; m < 4; ++m)
#pragma unroll
            for (int n = 0; n < 4; ++n) acc[m][n] = MFMA16(a[m], b[n], acc[m][n]);
    }

    // ---- phase 6: logits (waves 0-1) / V1 (waves 2-3) ----
    if (w < 2) {
#pragma unroll
        for (int n = 0; n < 4; ++n) {
            const float ad = att_dot[c0w + 16 * n + lr];
            const int h = 4 * w + n;
#pragma unroll
            for (int m = 0; m < 4; ++m) {
#pragma unroll
                for (int i = 0; i < 4; ++i) {
                    float s = slreluf_(acc[m][n][i]) * ad;
                    s += __shfl_xor(s, 1);
                    s += __shfl_xor(s, 2);
                    s += __shfl_xor(s, 4);
                    s += __shfl_xor(s, 8);
                    if (lr == 0) lgs[(16 * m + 4 * lg + i) * 8 + h] = s;
                }
            }
        }
    } else {
#pragma unroll
        for (int n = 0; n < 4; ++n) {
            const int cc = 64 * (w - 2) + 16 * n + lr;
            const float wi = w_int[cc];
#pragma unroll
            for (int m = 0; m < 4; ++m) {
#pragma unroll
                for (int i = 0; i < 4; ++i) {
                    const int r = 16 * m + 4 * lg + i;
                    int row = e0 + r;
                    row = (row < E) ? row : (E - 1);
                    const float v1 = siluf_(acc[m][n][i]) * ea[row] * wi;
                    const int byte = (r * 256 + cc * 2) ^ ((r & 7) << 4);
                    *reinterpret_cast<u16*>(regA + byte) = f2bf(v1);
                }
            }
        }
    }
    __syncthreads();

    // ---- phase 7: GEMM2  V = V1 @ Wv ----
    {
        f32x4 acc2[4][2];
#pragma unroll
        for (int m = 0; m < 4; ++m)
#pragma unroll
            for (int n = 0; n < 2; ++n) acc2[m][n] = (f32x4)(0.0f);
#pragma unroll
        for (int ks = 0; ks < 4; ++ks) {
            const int kk = lg * 8 + ks * 32;
            bf16x8 a2[4], b2[2];
#pragma unroll
            for (int m = 0; m < 4; ++m) {
                const int r = lr + 16 * m;
                const int byte = (r * 256 + kk * 2) ^ ((r & 7) << 4);
                a2[m] = *reinterpret_cast<const bf16x8*>(regA + byte);
            }
#pragma unroll
            for (int n = 0; n < 2; ++n) {
                const int j = 32 * w + 16 * n + lr;
                b2[n] = *reinterpret_cast<const bf16x8*>(&Wvt[(size_t)j * 128 + kk]);
            }
#pragma unroll
            for (int m = 0; m < 4; ++m)
#pragma unroll
                for (int n = 0; n < 2; ++n) acc2[m][n] = MFMA16(a2[m], b2[n], acc2[m][n]);
        }
        u16* Vout = (u16*)regB;  // Wts dead since phase 4
#pragma unroll
        for (int n = 0; n < 2; ++n) {
            const int j = 32 * w + 16 * n + lr;
#pragma unroll
            for (int m = 0; m < 4; ++m)
#pragma unroll
                for (int i = 0; i < 4; ++i) {
                    const int r = 16 * m + 4 * lg + i;
                    Vout[r * 128 + j] = f2bf(acc2[m][n][i]);
                }
        }
    }
    __syncthreads();

    // ---- phase 8: coalesced writeout of V and LG ----
    const uint4* vo = reinterpret_cast<const uint4*>(regB);
#pragma unroll
    for (int t = 0; t < 4; ++t) {
        const int idx = tid + 256 * t;
        const int row = idx >> 4;
        if (e0 + row < E)
            *reinterpret_cast<uint4*>(&V[(size_t)e0 * 128 + idx * 8]) = vo[idx];
    }
    if (tid < 128) {
        const int row = tid >> 1;  // 4 floats = half a row of 8 heads
        if (e0 + row < E)
            *reinterpret_cast<float4*>(&LG[(size_t)e0 * 8 + tid * 4]) =
                *reinterpret_cast<const float4*>(&lgs[tid * 4]);
    }
}

// ---------------- CSR aggregation with exact per-node max subtraction ----------------
__global__ __launch_bounds__(256) void aggregate_k(const int* __restrict__ rowptr,
                                                   const int* __restrict__ eids,
                                                   const float* __restrict__ LG,
                                                   const u16* __restrict__ V,
                                                   float* __restrict__ ACC, int Nn) {
    const int node = blockIdx.x * 4 + (threadIdx.x >> 6);
    const int lane = threadIdx.x & 63;
    if (node >= Nn) return;
    const int s = rowptr[node], t = rowptr[node + 1];
    const int h = lane >> 3;
    float m = -3.4e38f;
    for (int i = s; i < t; ++i) {
        const int e = eids[i];
        m = fmaxf(m, LG[(size_t)e * 8 + h]);
    }
    float a0 = 0.0f, a1 = 0.0f, ds = 0.0f;
    for (int i = s; i < t; ++i) {
        const int e = eids[i];
        const float exv = __expf(LG[(size_t)e * 8 + h] - m);
        const u32 vv = *reinterpret_cast<const u32*>(&V[(size_t)e * 128 + lane * 2]);
        a0 += exv * lo2f(vv);
        a1 += exv * hi2f(vv);
        ds += exv;
    }
    const float inv = 1.0f / (ds + 1e-16f);
    ACC[(size_t)node * 128 + lane * 2]     = a0 * inv;
    ACC[(size_t)node * 128 + lane * 2 + 1] = a1 * inv;
}

// ---------------- launch ----------------
extern "C" void kernel_launch(void* const* d_in, const int* in_sizes, int n_in,
                              void* d_out, int out_size, void* d_ws, size_t ws_size,
                              hipStream_t stream) {
    const float* node_feats = (const float*)d_in[0];
    const float* node_attr  = (const float*)d_in[1];
    const float* edge_attr  = (const float*)d_in[2];
    const float* edge_emb   = (const float*)d_in[3];
    const float* W_src      = (const float*)d_in[4];
    const float* b_src      = (const float*)d_in[5];
    const float* W_dst      = (const float*)d_in[6];
    const float* W_fc1      = (const float*)d_in[7];
    const float* b_fc1      = (const float*)d_in[8];
    const float* W_fc2      = (const float*)d_in[9];
    const float* b_fc2      = (const float*)d_in[10];
    const float* W_fc3      = (const float*)d_in[11];
    const float* W_alpha    = (const float*)d_in[12];
    const float* W_lin      = (const float*)d_in[13];
    const float* w_int      = (const float*)d_in[14];
    const float* W_val      = (const float*)d_in[15];
    const float* att_dot    = (const float*)d_in[16];
    const float* W_out      = (const float*)d_in[17];
    const float* b_out      = (const float*)d_in[18];
    const int* esrc         = (const int*)d_in[19];
    const int* edst         = (const int*)d_in[20];

    const int Nn = in_sizes[0] / 128;  // 30000
    const int E  = in_sizes[19];       // 480000

    char* w = (char*)d_ws;
    auto alloc = [&](size_t bytes) {
        char* p = w;
        w += (bytes + 255) & ~(size_t)255;
        return p;
    };
    u16* V      = (u16*)alloc((size_t)E * 128 * 2);    // 122.9 MB
    float* LG   = (float*)alloc((size_t)E * 8 * 4);    // 15.4 MB (own buffer: read/write live together in msg_attn_k)
    float* Psrc = (float*)alloc((size_t)Nn * 128 * 4);
    float* ACC  = Psrc;                                // Psrc dead after msg_attn_k
    float* Pdst = (float*)alloc((size_t)Nn * 128 * 4);
    int* deg    = (int*)alloc((size_t)Nn * 4);
    int* rowptr = (int*)alloc((size_t)(Nn + 1) * 4);
    int* cursor = (int*)alloc((size_t)Nn * 4);
    int* eids   = (int*)alloc((size_t)E * 4);
    u16* Wct    = (u16*)alloc(32768 * 2);
    u16* Wvt    = (u16*)alloc(16384 * 2);
    u16* Bt1    = (u16*)alloc(4096 * 2);
    u16* Bt2    = (u16*)alloc(4096 * 2);
    u16* Bt3    = (u16*)alloc(8192 * 2);

    // CSR build + weight prep
    hipMemsetAsync(deg, 0, (size_t)Nn * 4, stream);
    hist_k<<<(E + 255) / 256, 256, 0, stream>>>(edst, deg, E);
    scan_k<<<1, 1024, 0, stream>>>(deg, rowptr, cursor, Nn);
    fill_k<<<(E + 255) / 256, 256, 0, stream>>>(edst, cursor, eids, E);
    prep_w_k<<<256, 256, 0, stream>>>(W_alpha, W_lin, W_val, W_fc1, W_fc2, W_fc3,
                                      Wct, Wvt, Bt1, Bt2, Bt3);

    const int nb_node = (Nn + 63) / 64;  // 469
    const int nb_e    = (E + 63) / 64;   // 7500

    gemm_plain_k<128, 128><<<nb_node, 256, 0, stream>>>(node_feats, W_src, b_src, Psrc, Nn);
    gemm_plain_k<128, 128><<<nb_node, 256, 0, stream>>>(node_feats, W_dst, nullptr, Pdst, Nn);

    msg_attn_k<<<nb_e, 256, 0, stream>>>(edge_emb, node_attr, edge_attr, esrc, edst,
                                         Bt1, b_fc1, Bt2, b_fc2, Bt3,
                                         Psrc, Pdst, Wct, Wvt, att_dot, w_int,
                                         LG, V, E);

    aggregate_k<<<(Nn + 3) / 4, 256, 0, stream>>>(rowptr, eids, LG, V, ACC, Nn);

    gemm_plain_k<128, 128><<<nb_node, 256, 0, stream>>>(ACC, W_out, b_out, (float*)d_out, Nn);
}

// Round 7
// 641.639 us; speedup vs baseline: 3.5278x; 1.1242x over previous
//
#include <hip/hip_runtime.h>
#include <hip/hip_bf16.h>
#include <cstdint>
#include <cstddef>

// GraphAttentionLayer: N=30000, E=480000, C=128, H=8, DH=16, NB=32, NA=16, FC=64.
//
// R7 changes vs R6:
//   1. f2bf: software RTNE integer sequence -> __float2bfloat16 scalar cast
//      (compiler emits hardware v_cvt_pk_bf16_f32 pairs; T12/m240). This was
//      ~40 VALU ops per bf16x8 fragment load, ~5 per LDS C-write element.
//   2. Node projections + output projection: f32 VALU gemm_plain_k -> MFMA
//      proj_mfma_k (weights pre-transposed bf16 in prep_w_k, A cast in-reg,
//      f32 out). Same fragment recipe as msg_attn_k.
// Structure otherwise identical to R6 (fused msg_attn_k, CSR aggregate).

typedef unsigned short u16;
typedef unsigned int u32;
typedef __attribute__((ext_vector_type(8))) short bf16x8;
typedef __attribute__((ext_vector_type(4))) float f32x4;

union fu_ { float f; u32 u; };
static __device__ __forceinline__ float lo2f(u32 v) { fu_ x; x.u = v << 16; return x.f; }
static __device__ __forceinline__ float hi2f(u32 v) { fu_ x; x.u = v & 0xFFFF0000u; return x.f; }
static __device__ __forceinline__ u16 f2bf(float f) {
    union { __hip_bfloat16 h; u16 u; } c;
    c.h = __float2bfloat16(f);   // hardware cvt path (RTNE), see T12/m240
    return c.u;
}
static __device__ __forceinline__ u32 pack2(float a, float b) {
    return (u32)f2bf(a) | ((u32)f2bf(b) << 16);
}
static __device__ __forceinline__ float sigmoidf_(float x) { return 1.0f / (1.0f + __expf(-x)); }
static __device__ __forceinline__ float siluf_(float x)    { return x * sigmoidf_(x); }
static __device__ __forceinline__ float slreluf_(float x)  { return x * (0.2f + 0.8f * sigmoidf_(x)); }

#define MFMA16(a, b, c) __builtin_amdgcn_mfma_f32_16x16x32_bf16((a), (b), (c), 0, 0, 0)

static __device__ __forceinline__ bf16x8 ld8f_bf(const float* __restrict__ p) {
    const float4 x = *reinterpret_cast<const float4*>(p);
    const float4 y = *reinterpret_cast<const float4*>(p + 4);
    bf16x8 r;
    r[0] = (short)f2bf(x.x); r[1] = (short)f2bf(x.y);
    r[2] = (short)f2bf(x.z); r[3] = (short)f2bf(x.w);
    r[4] = (short)f2bf(y.x); r[5] = (short)f2bf(y.y);
    r[6] = (short)f2bf(y.z); r[7] = (short)f2bf(y.w);
    return r;
}

// ---------------- CSR build ----------------
__global__ void hist_k(const int* __restrict__ dst, int* __restrict__ deg, int E) {
    int i = blockIdx.x * blockDim.x + threadIdx.x;
    if (i < E) atomicAdd(&deg[dst[i]], 1);
}

__global__ void scan_k(const int* __restrict__ deg, int* __restrict__ rowptr,
                       int* __restrict__ cursor, int n) {
    __shared__ int part[1024];
    const int t = threadIdx.x;
    const int C = (n + 1023) / 1024;
    const int lo = t * C;
    const int hi = (lo + C < n) ? (lo + C) : n;
    int s = 0;
    for (int i = lo; i < hi; ++i) s += deg[i];
    part[t] = s;
    __syncthreads();
    for (int off = 1; off < 1024; off <<= 1) {
        int v = part[t];
        int u = (t >= off) ? part[t - off] : 0;
        __syncthreads();
        part[t] = v + u;
        __syncthreads();
    }
    int excl = (t == 0) ? 0 : part[t - 1];
    for (int i = lo; i < hi; ++i) {
        rowptr[i] = excl;
        cursor[i] = excl;
        excl += deg[i];
    }
    if (t == 1023) rowptr[n] = part[1023];
}

__global__ void fill_k(const int* __restrict__ dst, int* __restrict__ cursor,
                       int* __restrict__ eids, int E) {
    int i = blockIdx.x * blockDim.x + threadIdx.x;
    if (i < E) {
        int d = dst[i];
        int p = atomicAdd(&cursor[d], 1);
        eids[p] = i;
    }
}

// ---------------- weight prep (all transposed, bf16) ----------------
// Layout Wt[c][k] = W[k][c].  Total 114688 u16 -> grid 448x256.
__global__ void prep_w_k(const float* __restrict__ Wa, const float* __restrict__ Wl,
                         const float* __restrict__ Wv,
                         const float* __restrict__ W1, const float* __restrict__ W2,
                         const float* __restrict__ W3,
                         const float* __restrict__ Wsrc, const float* __restrict__ Wdst,
                         const float* __restrict__ Wout,
                         u16* __restrict__ Wct, u16* __restrict__ Wvt,
                         u16* __restrict__ Bt1, u16* __restrict__ Bt2,
                         u16* __restrict__ Bt3,
                         u16* __restrict__ Wst, u16* __restrict__ Wdt,
                         u16* __restrict__ Wot) {
    int idx = blockIdx.x * 256 + threadIdx.x;
    if (idx < 32768) {
        int c = idx >> 7, k = idx & 127;
        float v = (c < 128) ? Wa[(size_t)k * 128 + c] : Wl[(size_t)k * 128 + (c - 128)];
        Wct[idx] = f2bf(v);
    } else if (idx < 49152) {
        int t = idx - 32768;
        int j = t >> 7, c = t & 127;
        Wvt[t] = f2bf(Wv[(size_t)c * 128 + j]);
    } else if (idx < 53248) {
        int t = idx - 49152;
        int c = t >> 6, k = t & 63;
        Bt1[t] = f2bf(W1[(size_t)k * 64 + c]);
    } else if (idx < 57344) {
        int t = idx - 53248;
        int c = t >> 6, k = t & 63;
        Bt2[t] = f2bf(W2[(size_t)k * 64 + c]);
    } else if (idx < 65536) {
        int t = idx - 57344;
        int c = t >> 6, k = t & 63;
        Bt3[t] = f2bf(W3[(size_t)k * 128 + c]);
    } else if (idx < 81920) {
        int t = idx - 65536;
        int c = t >> 7, k = t & 127;
        Wst[t] = f2bf(Wsrc[(size_t)k * 128 + c]);
    } else if (idx < 98304) {
        int t = idx - 81920;
        int c = t >> 7, k = t & 127;
        Wdt[t] = f2bf(Wdst[(size_t)k * 128 + c]);
    } else if (idx < 114688) {
        int t = idx - 98304;
        int c = t >> 7, k = t & 127;
        Wot[t] = f2bf(Wout[(size_t)k * 128 + c]);
    }
}

// ---------------- MFMA projection GEMM: Out[M,128] = bf16(A[M,128]) @ Wt + bias ----------------
// Block 256 = 4 waves; tile 64 rows; wave w owns cols 32w..32w+31.
__global__ __launch_bounds__(256) void proj_mfma_k(const float* __restrict__ A,
                                                   const u16* __restrict__ Wt,
                                                   const float* __restrict__ bias,
                                                   float* __restrict__ Out, int M) {
    const int tid  = threadIdx.x;
    const int lane = tid & 63;
    const int w    = tid >> 6;
    const int lr   = lane & 15;
    const int lg   = lane >> 4;
    const int e0   = blockIdx.x * 64;

    f32x4 acc[4][2];
#pragma unroll
    for (int m = 0; m < 4; ++m)
#pragma unroll
        for (int n = 0; n < 2; ++n) acc[m][n] = (f32x4)(0.0f);

#pragma unroll
    for (int ks = 0; ks < 4; ++ks) {
        const int kk = lg * 8 + ks * 32;
        bf16x8 a[4], b[2];
#pragma unroll
        for (int m = 0; m < 4; ++m) {
            int row = e0 + lr + 16 * m;
            row = (row < M) ? row : (M - 1);
            a[m] = ld8f_bf(&A[(size_t)row * 128 + kk]);
        }
#pragma unroll
        for (int n = 0; n < 2; ++n) {
            const int c = 32 * w + 16 * n + lr;
            b[n] = *reinterpret_cast<const bf16x8*>(&Wt[(size_t)c * 128 + kk]);
        }
#pragma unroll
        for (int m = 0; m < 4; ++m)
#pragma unroll
            for (int n = 0; n < 2; ++n) acc[m][n] = MFMA16(a[m], b[n], acc[m][n]);
    }

#pragma unroll
    for (int n = 0; n < 2; ++n) {
        const int j = 32 * w + 16 * n + lr;
        const float bv = bias ? bias[j] : 0.0f;
#pragma unroll
        for (int m = 0; m < 4; ++m)
#pragma unroll
            for (int i = 0; i < 4; ++i) {
                const int row = e0 + 16 * m + 4 * lg + i;
                if (row < M) Out[(size_t)row * 128 + j] = acc[m][n][i] + bv;
            }
    }
}

// ---------------- fused radial MLP + message + attention + value ----------------
// Block 256 = 4 waves; tile = 64 edges; MSG lives only in LDS.
__global__ __launch_bounds__(256) void msg_attn_k(
    const float* __restrict__ eemb, const float* __restrict__ nattr,
    const float* __restrict__ ea,
    const int* __restrict__ src, const int* __restrict__ dst,
    const u16* __restrict__ Bt1, const float* __restrict__ b1,
    const u16* __restrict__ Bt2, const float* __restrict__ b2,
    const u16* __restrict__ Bt3,
    const float* __restrict__ Ps, const float* __restrict__ Pd,
    const u16* __restrict__ Wct, const u16* __restrict__ Wvt,
    const float* __restrict__ att_dot, const float* __restrict__ w_int,
    float* __restrict__ LG, u16* __restrict__ V, int E) {
    __shared__ __align__(16) char smem[51200];
    char* regA  = smem;           // H1s [0,8K) + H2s [8K,16K); later V1s (16K)
    char* regB  = smem + 16384;   // Wts (16K); later Vout (16K)
    char* regC  = smem + 32768;   // MSGs (16K)
    float* lgs  = (float*)(smem + 49152);  // 64*8 f32

    const int tid  = threadIdx.x;
    const int lane = tid & 63;
    const int w    = tid >> 6;
    const int lr   = lane & 15;
    const int lg   = lane >> 4;
    const int e0   = blockIdx.x * 64;

    // ---- phase 1: fc1  H1 = silu(WF @ W1 + b1), A direct from global ----
    {
        f32x4 acc1[4];
#pragma unroll
        for (int m = 0; m < 4; ++m) acc1[m] = (f32x4)(0.0f);
#pragma unroll
        for (int ks = 0; ks < 2; ++ks) {
            const int kk = lg * 8 + ks * 32;
            bf16x8 a[4];
#pragma unroll
            for (int m = 0; m < 4; ++m) {
                int row = e0 + lr + 16 * m;
                row = (row < E) ? row : (E - 1);
                const float* ap;
                if (kk < 32)      ap = &eemb[(size_t)row * 32 + kk];
                else if (kk < 48) ap = &nattr[(size_t)src[row] * 16 + (kk - 32)];
                else              ap = &nattr[(size_t)dst[row] * 16 + (kk - 48)];
                a[m] = ld8f_bf(ap);
            }
            const bf16x8 b = *reinterpret_cast<const bf16x8*>(&Bt1[(size_t)(16 * w + lr) * 64 + kk]);
#pragma unroll
            for (int m = 0; m < 4; ++m) acc1[m] = MFMA16(a[m], b, acc1[m]);
        }
        const int c = 16 * w + lr;
        const float bias = b1[c];
#pragma unroll
        for (int m = 0; m < 4; ++m)
#pragma unroll
            for (int i = 0; i < 4; ++i) {
                const int r = 16 * m + 4 * lg + i;
                const int byte = (r * 128 + c * 2) ^ ((r & 7) << 4);
                *reinterpret_cast<u16*>(regA + byte) = f2bf(siluf_(acc1[m][i] + bias));
            }
    }
    __syncthreads();

    // ---- phase 2: fc2  H2 = silu(H1 @ W2 + b2) ----
    {
        f32x4 acc2[4];
#pragma unroll
        for (int m = 0; m < 4; ++m) acc2[m] = (f32x4)(0.0f);
#pragma unroll
        for (int ks = 0; ks < 2; ++ks) {
            const int kk = lg * 8 + ks * 32;
            bf16x8 a[4];
#pragma unroll
            for (int m = 0; m < 4; ++m) {
                const int r = lr + 16 * m;
                const int byte = (r * 128 + kk * 2) ^ ((r & 7) << 4);
                a[m] = *reinterpret_cast<const bf16x8*>(regA + byte);
            }
            const bf16x8 b = *reinterpret_cast<const bf16x8*>(&Bt2[(size_t)(16 * w + lr) * 64 + kk]);
#pragma unroll
            for (int m = 0; m < 4; ++m) acc2[m] = MFMA16(a[m], b, acc2[m]);
        }
        const int c = 16 * w + lr;
        const float bias = b2[c];
#pragma unroll
        for (int m = 0; m < 4; ++m)
#pragma unroll
            for (int i = 0; i < 4; ++i) {
                const int r = 16 * m + 4 * lg + i;
                const int byte = (r * 128 + c * 2) ^ ((r & 7) << 4);
                *reinterpret_cast<u16*>(regA + 8192 + byte) = f2bf(siluf_(acc2[m][i] + bias));
            }
    }
    __syncthreads();

    // ---- phase 3: fc3  W = H2 @ W3 -> Wts ----
    {
        f32x4 acc3[2][4];
#pragma unroll
        for (int n = 0; n < 2; ++n)
#pragma unroll
            for (int m = 0; m < 4; ++m) acc3[n][m] = (f32x4)(0.0f);
#pragma unroll
        for (int ks = 0; ks < 2; ++ks) {
            const int kk = lg * 8 + ks * 32;
            bf16x8 a[4];
#pragma unroll
            for (int m = 0; m < 4; ++m) {
                const int r = lr + 16 * m;
                const int byte = (r * 128 + kk * 2) ^ ((r & 7) << 4);
                a[m] = *reinterpret_cast<const bf16x8*>(regA + 8192 + byte);
            }
            bf16x8 b[2];
#pragma unroll
            for (int n = 0; n < 2; ++n) {
                const int c = 32 * w + 16 * n + lr;
                b[n] = *reinterpret_cast<const bf16x8*>(&Bt3[(size_t)c * 64 + kk]);
            }
#pragma unroll
            for (int n = 0; n < 2; ++n)
#pragma unroll
                for (int m = 0; m < 4; ++m) acc3[n][m] = MFMA16(a[m], b[n], acc3[n][m]);
        }
#pragma unroll
        for (int n = 0; n < 2; ++n) {
            const int c = 32 * w + 16 * n + lr;
#pragma unroll
            for (int m = 0; m < 4; ++m)
#pragma unroll
                for (int i = 0; i < 4; ++i) {
                    const int r = 16 * m + 4 * lg + i;
                    const int byte = (r * 256 + c * 2) ^ ((r & 7) << 4);
                    *reinterpret_cast<u16*>(regB + byte) = f2bf(acc3[n][m][i]);
                }
        }
    }
    __syncthreads();

    // ---- phase 4: epilogue  MSG = (Ps[src]+Pd[dst]) * ea * W -> MSGs (LDS only) ----
#pragma unroll
    for (int t = 0; t < 4; ++t) {
        const int idx = tid + 256 * t;  // 64 rows x 16 chunks of 8 cols
        const int r = idx >> 4;
        const int c8 = (idx & 15) * 8;
        const int row = e0 + r;
        if (row >= E) continue;
        const int byte = (r * 256 + c8 * 2) ^ ((r & 7) << 4);
        const uint4 wv = *reinterpret_cast<const uint4*>(regB + byte);
        const float wt[8] = {lo2f(wv.x), hi2f(wv.x), lo2f(wv.y), hi2f(wv.y),
                             lo2f(wv.z), hi2f(wv.z), lo2f(wv.w), hi2f(wv.w)};
        const int s = src[row], d = dst[row];
        const float eav = ea[row];
        const float4 ps0 = *reinterpret_cast<const float4*>(&Ps[(size_t)s * 128 + c8]);
        const float4 ps1 = *reinterpret_cast<const float4*>(&Ps[(size_t)s * 128 + c8 + 4]);
        const float4 pd0 = *reinterpret_cast<const float4*>(&Pd[(size_t)d * 128 + c8]);
        const float4 pd1 = *reinterpret_cast<const float4*>(&Pd[(size_t)d * 128 + c8 + 4]);
        float m[8];
        m[0] = (ps0.x + pd0.x) * eav * wt[0];
        m[1] = (ps0.y + pd0.y) * eav * wt[1];
        m[2] = (ps0.z + pd0.z) * eav * wt[2];
        m[3] = (ps0.w + pd0.w) * eav * wt[3];
        m[4] = (ps1.x + pd1.x) * eav * wt[4];
        m[5] = (ps1.y + pd1.y) * eav * wt[5];
        m[6] = (ps1.z + pd1.z) * eav * wt[6];
        m[7] = (ps1.w + pd1.w) * eav * wt[7];
        u32 p0 = pack2(m[0], m[1]), p1 = pack2(m[2], m[3]);
        u32 p2 = pack2(m[4], m[5]), p3 = pack2(m[6], m[7]);
        *reinterpret_cast<uint4*>(regC + byte) = make_uint4(p0, p1, p2, p3);
    }
    __syncthreads();

    // ---- phase 5: GEMM1  scores|v1pre = MSG @ [Wa|Wl], A from MSGs LDS ----
    f32x4 acc[4][4];
#pragma unroll
    for (int m = 0; m < 4; ++m)
#pragma unroll
        for (int n = 0; n < 4; ++n) acc[m][n] = (f32x4)(0.0f);

    const int c0w = w * 64;
#pragma unroll
    for (int ks = 0; ks < 4; ++ks) {
        const int kk = lg * 8 + ks * 32;
        bf16x8 a[4], b[4];
#pragma unroll
        for (int m = 0; m < 4; ++m) {
            const int r = lr + 16 * m;
            const int byte = (r * 256 + kk * 2) ^ ((r & 7) << 4);
            a[m] = *reinterpret_cast<const bf16x8*>(regC + byte);
        }
#pragma unroll
        for (int n = 0; n < 4; ++n) {
            const int c = c0w + lr + 16 * n;
            b[n] = *reinterpret_cast<const bf16x8*>(&Wct[(size_t)c * 128 + kk]);
        }
#pragma unroll
        for (int m = 0; m < 4; ++m)
#pragma unroll
            for (int n = 0; n < 4; ++n) acc[m][n] = MFMA16(a[m], b[n], acc[m][n]);
    }

    // ---- phase 6: logits (waves 0-1) / V1 (waves 2-3) ----
    if (w < 2) {
#pragma unroll
        for (int n = 0; n < 4; ++n) {
            const float ad = att_dot[c0w + 16 * n + lr];
            const int h = 4 * w + n;
#pragma unroll
            for (int m = 0; m < 4; ++m) {
#pragma unroll
                for (int i = 0; i < 4; ++i) {
                    float s = slreluf_(acc[m][n][i]) * ad;
                    s += __shfl_xor(s, 1);
                    s += __shfl_xor(s, 2);
                    s += __shfl_xor(s, 4);
                    s += __shfl_xor(s, 8);
                    if (lr == 0) lgs[(16 * m + 4 * lg + i) * 8 + h] = s;
                }
            }
        }
    } else {
#pragma unroll
        for (int n = 0; n < 4; ++n) {
            const int cc = 64 * (w - 2) + 16 * n + lr;
            const float wi = w_int[cc];
#pragma unroll
            for (int m = 0; m < 4; ++m) {
#pragma unroll
                for (int i = 0; i < 4; ++i) {
                    const int r = 16 * m + 4 * lg + i;
                    int row = e0 + r;
                    row = (row < E) ? row : (E - 1);
                    const float v1 = siluf_(acc[m][n][i]) * ea[row] * wi;
                    const int byte = (r * 256 + cc * 2) ^ ((r & 7) << 4);
                    *reinterpret_cast<u16*>(regA + byte) = f2bf(v1);
                }
            }
        }
    }
    __syncthreads();

    // ---- phase 7: GEMM2  V = V1 @ Wv ----
    {
        f32x4 acc2[4][2];
#pragma unroll
        for (int m = 0; m < 4; ++m)
#pragma unroll
            for (int n = 0; n < 2; ++n) acc2[m][n] = (f32x4)(0.0f);
#pragma unroll
        for (int ks = 0; ks < 4; ++ks) {
            const int kk = lg * 8 + ks * 32;
            bf16x8 a2[4], b2[2];
#pragma unroll
            for (int m = 0; m < 4; ++m) {
                const int r = lr + 16 * m;
                const int byte = (r * 256 + kk * 2) ^ ((r & 7) << 4);
                a2[m] = *reinterpret_cast<const bf16x8*>(regA + byte);
            }
#pragma unroll
            for (int n = 0; n < 2; ++n) {
                const int j = 32 * w + 16 * n + lr;
                b2[n] = *reinterpret_cast<const bf16x8*>(&Wvt[(size_t)j * 128 + kk]);
            }
#pragma unroll
            for (int m = 0; m < 4; ++m)
#pragma unroll
                for (int n = 0; n < 2; ++n) acc2[m][n] = MFMA16(a2[m], b2[n], acc2[m][n]);
        }
        u16* Vout = (u16*)regB;  // Wts dead since phase 4
#pragma unroll
        for (int n = 0; n < 2; ++n) {
            const int j = 32 * w + 16 * n + lr;
#pragma unroll
            for (int m = 0; m < 4; ++m)
#pragma unroll
                for (int i = 0; i < 4; ++i) {
                    const int r = 16 * m + 4 * lg + i;
                    Vout[r * 128 + j] = f2bf(acc2[m][n][i]);
                }
        }
    }
    __syncthreads();

    // ---- phase 8: coalesced writeout of V and LG ----
    const uint4* vo = reinterpret_cast<const uint4*>(regB);
#pragma unroll
    for (int t = 0; t < 4; ++t) {
        const int idx = tid + 256 * t;
        const int row = idx >> 4;
        if (e0 + row < E)
            *reinterpret_cast<uint4*>(&V[(size_t)e0 * 128 + idx * 8]) = vo[idx];
    }
    if (tid < 128) {
        const int row = tid >> 1;
        if (e0 + row < E)
            *reinterpret_cast<float4*>(&LG[(size_t)e0 * 8 + tid * 4]) =
                *reinterpret_cast<const float4*>(&lgs[tid * 4]);
    }
}

// ---------------- CSR aggregation with exact per-node max subtraction ----------------
__global__ __launch_bounds__(256) void aggregate_k(const int* __restrict__ rowptr,
                                                   const int* __restrict__ eids,
                                                   const float* __restrict__ LG,
                                                   const u16* __restrict__ V,
                                                   float* __restrict__ ACC, int Nn) {
    const int node = blockIdx.x * 4 + (threadIdx.x >> 6);
    const int lane = threadIdx.x & 63;
    if (node >= Nn) return;
    const int s = rowptr[node], t = rowptr[node + 1];
    const int h = lane >> 3;
    float m = -3.4e38f;
    for (int i = s; i < t; ++i) {
        const int e = eids[i];
        m = fmaxf(m, LG[(size_t)e * 8 + h]);
    }
    float a0 = 0.0f, a1 = 0.0f, ds = 0.0f;
    for (int i = s; i < t; ++i) {
        const int e = eids[i];
        const float exv = __expf(LG[(size_t)e * 8 + h] - m);
        const u32 vv = *reinterpret_cast<const u32*>(&V[(size_t)e * 128 + lane * 2]);
        a0 += exv * lo2f(vv);
        a1 += exv * hi2f(vv);
        ds += exv;
    }
    const float inv = 1.0f / (ds + 1e-16f);
    ACC[(size_t)node * 128 + lane * 2]     = a0 * inv;
    ACC[(size_t)node * 128 + lane * 2 + 1] = a1 * inv;
}

// ---------------- launch ----------------
extern "C" void kernel_launch(void* const* d_in, const int* in_sizes, int n_in,
                              void* d_out, int out_size, void* d_ws, size_t ws_size,
                              hipStream_t stream) {
    const float* node_feats = (const float*)d_in[0];
    const float* node_attr  = (const float*)d_in[1];
    const float* edge_attr  = (const float*)d_in[2];
    const float* edge_emb   = (const float*)d_in[3];
    const float* W_src      = (const float*)d_in[4];
    const float* b_src      = (const float*)d_in[5];
    const float* W_dst      = (const float*)d_in[6];
    const float* W_fc1      = (const float*)d_in[7];
    const float* b_fc1      = (const float*)d_in[8];
    const float* W_fc2      = (const float*)d_in[9];
    const float* b_fc2      = (const float*)d_in[10];
    const float* W_fc3      = (const float*)d_in[11];
    const float* W_alpha    = (const float*)d_in[12];
    const float* W_lin      = (const float*)d_in[13];
    const float* w_int      = (const float*)d_in[14];
    const float* W_val      = (const float*)d_in[15];
    const float* att_dot    = (const float*)d_in[16];
    const float* W_out      = (const float*)d_in[17];
    const float* b_out      = (const float*)d_in[18];
    const int* esrc         = (const int*)d_in[19];
    const int* edst         = (const int*)d_in[20];

    const int Nn = in_sizes[0] / 128;  // 30000
    const int E  = in_sizes[19];       // 480000

    char* w = (char*)d_ws;
    auto alloc = [&](size_t bytes) {
        char* p = w;
        w += (bytes + 255) & ~(size_t)255;
        return p;
    };
    u16* V      = (u16*)alloc((size_t)E * 128 * 2);    // 122.9 MB
    float* LG   = (float*)alloc((size_t)E * 8 * 4);    // 15.4 MB
    float* Psrc = (float*)alloc((size_t)Nn * 128 * 4);
    float* ACC  = Psrc;                                // Psrc dead after msg_attn_k
    float* Pdst = (float*)alloc((size_t)Nn * 128 * 4);
    int* deg    = (int*)alloc((size_t)Nn * 4);
    int* rowptr = (int*)alloc((size_t)(Nn + 1) * 4);
    int* cursor = (int*)alloc((size_t)Nn * 4);
    int* eids   = (int*)alloc((size_t)E * 4);
    u16* Wct    = (u16*)alloc(32768 * 2);
    u16* Wvt    = (u16*)alloc(16384 * 2);
    u16* Bt1    = (u16*)alloc(4096 * 2);
    u16* Bt2    = (u16*)alloc(4096 * 2);
    u16* Bt3    = (u16*)alloc(8192 * 2);
    u16* Wst    = (u16*)alloc(16384 * 2);
    u16* Wdt    = (u16*)alloc(16384 * 2);
    u16* Wot    = (u16*)alloc(16384 * 2);

    // CSR build + weight prep
    hipMemsetAsync(deg, 0, (size_t)Nn * 4, stream);
    hist_k<<<(E + 255) / 256, 256, 0, stream>>>(edst, deg, E);
    scan_k<<<1, 1024, 0, stream>>>(deg, rowptr, cursor, Nn);
    fill_k<<<(E + 255) / 256, 256, 0, stream>>>(edst, cursor, eids, E);
    prep_w_k<<<448, 256, 0, stream>>>(W_alpha, W_lin, W_val, W_fc1, W_fc2, W_fc3,
                                      W_src, W_dst, W_out,
                                      Wct, Wvt, Bt1, Bt2, Bt3, Wst, Wdt, Wot);

    const int nb_node = (Nn + 63) / 64;  // 469
    const int nb_e    = (E + 63) / 64;   // 7500

    proj_mfma_k<<<nb_node, 256, 0, stream>>>(node_feats, Wst, b_src, Psrc, Nn);
    proj_mfma_k<<<nb_node, 256, 0, stream>>>(node_feats, Wdt, nullptr, Pdst, Nn);

    msg_attn_k<<<nb_e, 256, 0, stream>>>(edge_emb, node_attr, edge_attr, esrc, edst,
                                         Bt1, b_fc1, Bt2, b_fc2, Bt3,
                                         Psrc, Pdst, Wct, Wvt, att_dot, w_int,
                                         LG, V, E);

    aggregate_k<<<(Nn + 3) / 4, 256, 0, stream>>>(rowptr, eids, LG, V, ACC, Nn);

    proj_mfma_k<<<nb_node, 256, 0, stream>>>(ACC, Wot, b_out, (float*)d_out, Nn);
}